// Round 4
// baseline (634.195 us; speedup 1.0000x reference)
//
#include <hip/hip_runtime.h>

// FWLNet: GCN x2 -> outer-product tensor -> two 65->64 maps -> 64x batched
// 1024^3 GEMM (prod) -> 129->64 map -> graph-norm(axis0) -> sym-product ->
// gather 8192 positions -> dot with ldW.
//
// R4: ALL external inputs are FLOAT32 (per reference dtypes), output FLOAT32.
// Previous rounds read them as bf16 -> low-half garbage (~1e8) -> f32 overflow
// in stats -> 0*inf = NaN in normB -> NaN everywhere. Internal tensors stay
// bf16 for the MFMA path.
//
// ws layout (bytes):
//   0         xf    (1024x64 f32)
//   262144    h     (1024x64 f32)
//   524288    agg   (1024x64 f32)
//   786432    deg   (1024 f32)
//   790528    xb    (1024x64 bf16)
//   921600    eim   (1024x1024 u8)
//   1970176   normA (1024x64 f32)
//   2232320   normB (1024x64 f32)
//   2494464   x1tg  (16x1024x1024 bf16) = 33554432
//   36048896  x2tg  (16x1024x1024 bf16) = 33554432
//   69603328  prod/T(64x1024x1024 bf16) = 134217728
// total 203821056 B ~= 194.4 MB

typedef unsigned short u16;
typedef unsigned int u32;

#define DI static __device__ __forceinline__

DI float bf2f(u16 u) { union { u32 i; float f; } v; v.i = ((u32)u) << 16; return v.f; }
DI u16 f2bf(float f) {
  union { float f; u32 i; } v; v.f = f;
  u32 u = v.i;
  return (u16)((u + 0x7fffu + ((u >> 16) & 1u)) >> 16);
}

typedef __bf16 bf16x8 __attribute__((ext_vector_type(8)));
typedef float f32x4 __attribute__((ext_vector_type(4)));

#define MFMA16(a, b, c) __builtin_amdgcn_mfma_f32_16x16x32_bf16((a), (b), (c), 0, 0, 0)

// ---------------- node pipeline ----------------

__global__ void k_setup(const int* __restrict__ xids, const float* __restrict__ emb,
                        float* __restrict__ xf, float* __restrict__ deg,
                        u32* __restrict__ eimu) {
  int g = blockIdx.x * 256 + threadIdx.x;  // grid 1024
  if (g < 262144) eimu[g] = 0u;
  if (g < 1024) deg[g] = 1.0f;  // self-loop
  if (g < 65536) {
    int i = g >> 6, d = g & 63;
    xf[g] = emb[xids[i] * 64 + d];
  }
}

__global__ void k_edges(const int* __restrict__ ei, float* __restrict__ deg,
                        unsigned char* __restrict__ eim) {
  int e = blockIdx.x * 256 + threadIdx.x;  // grid 64
  if (e < 16384) {
    int s = ei[e], d = ei[16384 + e];
    atomicAdd(&deg[d], 1.0f);
    eim[s * 1024 + d] = 1;  // set semantics: duplicate writes benign
  }
}

// h = xf @ W;  agg = h/deg (self-loop) + gb
__global__ void k_gemm_node(const float* __restrict__ xf, const float* __restrict__ W,
                            const float* __restrict__ gb, const float* __restrict__ deg,
                            float* __restrict__ h, float* __restrict__ agg) {
  __shared__ float xrow[64];
  int i = blockIdx.x, c = threadIdx.x;  // grid 1024 x 64
  xrow[c] = xf[i * 64 + c];
  __syncthreads();
  float s = 0.f;
#pragma unroll
  for (int d = 0; d < 64; ++d) s += xrow[d] * W[d * 64 + c];
  h[i * 64 + c] = s;
  agg[i * 64 + c] = s / deg[i] + gb[c];
}

__global__ void k_agg(const int* __restrict__ ei, const float* __restrict__ deg,
                      const float* __restrict__ h, float* __restrict__ agg) {
  int g = blockIdx.x * 256 + threadIdx.x;  // grid 4096 -> e x c
  int e = g >> 6, c = g & 63;
  int s = ei[e], d = ei[16384 + e];
  float nrm = rsqrtf(deg[s]) * rsqrtf(deg[d]);
  atomicAdd(&agg[d * 64 + c], nrm * h[s * 64 + c]);
}

__global__ void k_gnorm(const float* __restrict__ agg, const float* __restrict__ gw,
                        const float* __restrict__ gbb, const float* __restrict__ ga,
                        float* __restrict__ xf, u16* __restrict__ xb, int last) {
  int c = blockIdx.x, t = threadIdx.x;  // grid 64 x 256
  float s = 0.f, ss = 0.f;
  for (int i = t; i < 1024; i += 256) {
    float v = agg[i * 64 + c];
    s += v; ss += v * v;
  }
  __shared__ float Ls[256], Lss[256];
  Ls[t] = s; Lss[t] = ss;
  __syncthreads();
  for (int off = 128; off > 0; off >>= 1) {
    if (t < off) { Ls[t] += Ls[t + off]; Lss[t] += Lss[t + off]; }
    __syncthreads();
  }
  float m = Ls[0] * (1.f / 1024.f);
  float a = ga[c];
  float var = Lss[0] * (1.f / 1024.f) - (2.f * a - a * a) * m * m;
  float sc = gw[c] * rsqrtf(fmaxf(var, 0.f) + 1e-5f);
  float bb = gbb[c];
  for (int i = t; i < 1024; i += 256) {
    float v = agg[i * 64 + c];
    float y = fmaxf(sc * (v - a * m) + bb, 0.f);
    xf[i * 64 + c] = y;
    if (last) xb[i * 64 + c] = f2bf(y);
  }
}

// ---------------- x1t / x2T builder (16 channels per launch) ----------------
// which=0: x1tg[cl][i][k] = relu( sum_d x[i,d]*m1W[d,c]*x[k,d] + eim[i,k]*m1W[64,c] + m1b[c] )
// which=1: x2tg[cl][j][k] = relu( sum_d x[j,d]*m2W[d,c]*x[k,d] + eim[k,j]*m2W[64,c] + m2b[c] )
__global__ __launch_bounds__(256, 2) void k_build12(
    const u16* __restrict__ xbg, const unsigned char* __restrict__ eim,
    const float* __restrict__ m1W, const float* __restrict__ m1b,
    const float* __restrict__ m2W, const float* __restrict__ m2b,
    u16* __restrict__ x1tg, u16* __restrict__ x2tg, int cbase) {
  __shared__ u16 As[128][80];  // pad 64->80 keeps 16B row alignment
  __shared__ u16 Bs[128][80];
  __shared__ unsigned char El[128][128];
  __shared__ float wsc[64];
  int b = blockIdx.x;  // grid 2048 = 2(which) x 64 tiles x 16 ch
  int cl = b & 15;
  int c = cbase + cl;
  int rest = b >> 4;
  int which = rest >> 6;
  int t6 = rest & 63;
  int rbase = (t6 >> 3) * 128, sbase = (t6 & 7) * 128;
  const float* W = which ? m2W : m1W;
  const float* bias = which ? m2b : m1b;
  u16* outp = (which ? x2tg : x1tg) + (size_t)cl * 1048576;
  int t = threadIdx.x;
  if (t < 64) wsc[t] = W[t * 64 + c];
  __syncthreads();
  {
    int row = t >> 1, half = t & 1;
    const u32* ga = (const u32*)(xbg + (rbase + row) * 64 + half * 32);
    u32* dstA = (u32*)&As[row][half * 32];
#pragma unroll
    for (int k = 0; k < 16; ++k) {
      u32 u = ga[k];
      float f0 = bf2f((u16)(u & 0xffffu)) * wsc[half * 32 + 2 * k];
      float f1 = bf2f((u16)(u >> 16)) * wsc[half * 32 + 2 * k + 1];
      dstA[k] = (u32)f2bf(f0) | ((u32)f2bf(f1) << 16);
    }
    const u32* gB = (const u32*)(xbg + (sbase + row) * 64 + half * 32);
    u32* dstB = (u32*)&Bs[row][half * 32];
#pragma unroll
    for (int k = 0; k < 16; ++k) dstB[k] = gB[k];
    int ab = which ? sbase : rbase;
    int bb = which ? rbase : sbase;
    const u32* gE = (const u32*)(eim + (size_t)(ab + row) * 1024 + bb + half * 64);
    u32* dstE = (u32*)&El[row][half * 64];
#pragma unroll
    for (int k = 0; k < 16; ++k) dstE[k] = gE[k];
  }
  __syncthreads();
  int lane = t & 63, w = t >> 6;
  int q = lane >> 4, r = lane & 15;
  int wr = w >> 1, wc = w & 1;
  f32x4 z4 = {0.f, 0.f, 0.f, 0.f};
  f32x4 acc[4][4];
#pragma unroll
  for (int mi = 0; mi < 4; ++mi)
#pragma unroll
    for (int ni = 0; ni < 4; ++ni) acc[mi][ni] = z4;
#pragma unroll
  for (int ks = 0; ks < 2; ++ks) {
    bf16x8 af[4], bfr[4];
#pragma unroll
    for (int mi = 0; mi < 4; ++mi)
      af[mi] = *(const bf16x8*)&As[wr * 64 + mi * 16 + r][ks * 32 + q * 8];
#pragma unroll
    for (int ni = 0; ni < 4; ++ni)
      bfr[ni] = *(const bf16x8*)&Bs[wc * 64 + ni * 16 + r][ks * 32 + q * 8];
#pragma unroll
    for (int mi = 0; mi < 4; ++mi)
#pragma unroll
      for (int ni = 0; ni < 4; ++ni) acc[mi][ni] = MFMA16(af[mi], bfr[ni], acc[mi][ni]);
  }
  float w64 = W[64 * 64 + c];
  float bsv = bias[c];
#pragma unroll
  for (int mi = 0; mi < 4; ++mi) {
#pragma unroll
    for (int ni = 0; ni < 4; ++ni) {
      int col = wc * 64 + ni * 16 + r;
#pragma unroll
      for (int tt = 0; tt < 4; ++tt) {
        int row2 = wr * 64 + mi * 16 + q * 4 + tt;
        float e = (float)(which ? El[col][row2] : El[row2][col]);
        float val = acc[mi][ni][tt] + e * w64 + bsv;
        outp[(size_t)(rbase + row2) * 1024 + (sbase + col)] = f2bf(fmaxf(val, 0.f));
      }
    }
  }
}

// ---------------- batched prod GEMM (16 channels per launch) ----------------
// prod[cbase+cl] = x1tg[cl] (MxK row-major) @ x2tg[cl]^T  (x2tg is B^T layout)
__global__ __launch_bounds__(256, 2) void k_prodgemm(
    const u16* __restrict__ x1tg, const u16* __restrict__ x2tg,
    u16* __restrict__ prod, int cbase) {
  __shared__ u16 As[128 * 64];
  __shared__ u16 Bs[128 * 64];
  int b = blockIdx.x;  // grid 1024 = 64 tiles x 16 ch (cl in low bits)
  int cl = b & 15;
  int tile = b >> 4;
  int i0 = (tile >> 3) * 128, j0 = (tile & 7) * 128;
  const u16* Ap = x1tg + (size_t)cl * 1048576;
  const u16* Bp = x2tg + (size_t)cl * 1048576;
  u16* Pp = prod + (size_t)(cbase + cl) * 1048576;
  int t = threadIdx.x, lane = t & 63, w = t >> 6;
  int q = lane >> 4, r = lane & 15;
  int wr = w >> 1, wc = w & 1;
  int srow = t >> 1, shalf = t & 1;  // staging: 2 threads/row, 32 cols each
  f32x4 z4 = {0.f, 0.f, 0.f, 0.f};
  f32x4 acc[4][4];
#pragma unroll
  for (int mi = 0; mi < 4; ++mi)
#pragma unroll
    for (int ni = 0; ni < 4; ++ni) acc[mi][ni] = z4;
  for (int kk = 0; kk < 1024; kk += 64) {
    const uint4* gA = (const uint4*)(Ap + (size_t)(i0 + srow) * 1024 + kk + shalf * 32);
    const uint4* gB = (const uint4*)(Bp + (size_t)(j0 + srow) * 1024 + kk + shalf * 32);
    uint4 a0 = gA[0], a1 = gA[1], a2 = gA[2], a3 = gA[3];
    uint4 b0 = gB[0], b1 = gB[1], b2 = gB[2], b3 = gB[3];
    __syncthreads();  // frag reads of previous iter done before overwrite
    uint4* dA = (uint4*)&As[srow * 64 + shalf * 32];
    dA[0] = a0; dA[1] = a1; dA[2] = a2; dA[3] = a3;
    uint4* dB = (uint4*)&Bs[srow * 64 + shalf * 32];
    dB[0] = b0; dB[1] = b1; dB[2] = b2; dB[3] = b3;
    __syncthreads();
#pragma unroll
    for (int ks = 0; ks < 2; ++ks) {
      bf16x8 af[4], bfr[4];
#pragma unroll
      for (int mi = 0; mi < 4; ++mi)
        af[mi] = *(const bf16x8*)&As[(wr * 64 + mi * 16 + r) * 64 + ks * 32 + q * 8];
#pragma unroll
      for (int ni = 0; ni < 4; ++ni)
        bfr[ni] = *(const bf16x8*)&Bs[(wc * 64 + ni * 16 + r) * 64 + ks * 32 + q * 8];
#pragma unroll
      for (int mi = 0; mi < 4; ++mi)
#pragma unroll
        for (int ni = 0; ni < 4; ++ni) acc[mi][ni] = MFMA16(af[mi], bfr[ni], acc[mi][ni]);
    }
  }
#pragma unroll
  for (int mi = 0; mi < 4; ++mi) {
#pragma unroll
    for (int ni = 0; ni < 4; ++ni) {
      int col = wc * 64 + ni * 16 + r;
#pragma unroll
      for (int tt = 0; tt < 4; ++tt) {
        int row2 = wr * 64 + mi * 16 + q * 4 + tt;
        Pp[(size_t)(i0 + row2) * 1024 + j0 + col] = f2bf(acc[mi][ni][tt]);
      }
    }
  }
}

// ---------------- T = [x_i*x_j | eim | prod] @ m3W + b3 (IN PLACE over prod) --
// one block per i; A-tile [128 j][128 k] = [xpart | prodpart]; eim in epilogue.
// PT is read as prod[c][i][j] and overwritten as T[c][i][j] — block-private,
// all reads of a j-chunk precede its writes (barrier between), chunks disjoint.
__global__ __launch_bounds__(256, 2) void k_buildT(
    const u16* __restrict__ xbg, const unsigned char* __restrict__ eim,
    u16* PT, const float* __restrict__ m3W, const float* __restrict__ m3b) {
  __shared__ u16 A[128][136];  // 272B rows: 16B-aligned fragment reads
  __shared__ u16 Wt[64][136];  // Wt[c][k]: k<64 -> m3W[k][c], k>=64 -> m3W[k+1][c]
  __shared__ float xi[64];
  int i = blockIdx.x;  // grid 1024
  int t = threadIdx.x, lane = t & 63, w = t >> 6;
  int q = lane >> 4, r = lane & 15;
  if (t < 64) xi[t] = bf2f(xbg[i * 64 + t]);
  {
    int row = t >> 1, half = t & 1;
    int rsrc = row < 64 ? row : row + 1;  // skip eim row 64
    const float4* gw = (const float4*)(m3W + rsrc * 64 + half * 32);
#pragma unroll
    for (int k = 0; k < 8; ++k) {
      float4 f = gw[k];
      Wt[half * 32 + 4 * k + 0][row] = f2bf(f.x);
      Wt[half * 32 + 4 * k + 1][row] = f2bf(f.y);
      Wt[half * 32 + 4 * k + 2][row] = f2bf(f.z);
      Wt[half * 32 + 4 * k + 3][row] = f2bf(f.w);
    }
  }
  float w64c[4], b3c[4];
#pragma unroll
  for (int ni = 0; ni < 4; ++ni) {
    int cc = ni * 16 + r;
    w64c[ni] = m3W[64 * 64 + cc];
    b3c[ni] = m3b[cc];
  }
  for (int jc = 0; jc < 8; ++jc) {
    int j0 = jc * 128;
    __syncthreads();  // guards Wt/xi (jc=0) and A reuse (jc>0)
    {
      int jj = t >> 1, half = t & 1;
      const u32* gx = (const u32*)(xbg + (j0 + jj) * 64 + half * 32);
      u32* dst = (u32*)&A[jj][half * 32];
#pragma unroll
      for (int k = 0; k < 16; ++k) {
        u32 u = gx[k];
        float f0 = bf2f((u16)(u & 0xffffu)) * xi[half * 32 + 2 * k];
        float f1 = bf2f((u16)(u >> 16)) * xi[half * 32 + 2 * k + 1];
        dst[k] = (u32)f2bf(f0) | ((u32)f2bf(f1) << 16);
      }
      int e = t >> 2, part = t & 3;  // thread covers 64B of prod row seg
      const u32* gp = (const u32*)(PT + (size_t)e * 1048576 + (size_t)i * 1024 + j0 + part * 32);
#pragma unroll
      for (int k = 0; k < 16; ++k) {
        u32 u = gp[k];
        A[part * 32 + 2 * k][64 + e] = (u16)(u & 0xffffu);
        A[part * 32 + 2 * k + 1][64 + e] = (u16)(u >> 16);
      }
    }
    __syncthreads();
    f32x4 z4 = {0.f, 0.f, 0.f, 0.f};
    f32x4 acc[2][4];
#pragma unroll
    for (int mi = 0; mi < 2; ++mi)
#pragma unroll
      for (int ni = 0; ni < 4; ++ni) acc[mi][ni] = z4;
#pragma unroll
    for (int ks = 0; ks < 4; ++ks) {
      bf16x8 af[2], bfr[4];
#pragma unroll
      for (int mi = 0; mi < 2; ++mi)
        af[mi] = *(const bf16x8*)&A[w * 32 + mi * 16 + r][ks * 32 + q * 8];
#pragma unroll
      for (int ni = 0; ni < 4; ++ni)
        bfr[ni] = *(const bf16x8*)&Wt[ni * 16 + r][ks * 32 + q * 8];
#pragma unroll
      for (int mi = 0; mi < 2; ++mi)
#pragma unroll
        for (int ni = 0; ni < 4; ++ni) acc[mi][ni] = MFMA16(af[mi], bfr[ni], acc[mi][ni]);
    }
#pragma unroll
    for (int mi = 0; mi < 2; ++mi) {
#pragma unroll
      for (int tt = 0; tt < 4; ++tt) {
        int jj = w * 32 + mi * 16 + q * 4 + tt;
        float ev = (float)eim[(size_t)i * 1024 + j0 + jj];
#pragma unroll
        for (int ni = 0; ni < 4; ++ni) {
          int cc = ni * 16 + r;
          float val = acc[mi][ni][tt] + ev * w64c[ni] + b3c[ni];
          PT[(size_t)cc * 1048576 + (size_t)i * 1024 + j0 + jj] = f2bf(val);
        }
      }
    }
  }
}

// ---------------- graph-norm stats over axis 0 (T layout [c][i][j]) ----------
__global__ void k_stats(const u16* __restrict__ Tg, const float* __restrict__ gn3w,
                        const float* __restrict__ gn3b, const float* __restrict__ gn3a,
                        float* __restrict__ normA, float* __restrict__ normB) {
  int b = blockIdx.x;  // grid 256 = 64 c x 4 j-chunks; block 1024 threads
  int c = b >> 2, jc = b & 3;
  int t = threadIdx.x;
  int jl = t & 255, seg = t >> 8;
  int j = jc * 256 + jl;
  const u16* base = Tg + (size_t)c * 1048576 + j;
  float s = 0.f, ss = 0.f;
#pragma unroll 4
  for (int i = seg * 256; i < seg * 256 + 256; ++i) {
    float v = bf2f(base[(size_t)i * 1024]);
    s += v; ss += v * v;
  }
  __shared__ float Ls[1024], Lss[1024];
  Ls[t] = s; Lss[t] = ss;
  __syncthreads();
  if (seg == 0) {
    float sum = Ls[jl] + Ls[jl + 256] + Ls[jl + 512] + Ls[jl + 768];
    float ssum = Lss[jl] + Lss[jl + 256] + Lss[jl + 512] + Lss[jl + 768];
    float m = sum * (1.f / 1024.f);
    float a = gn3a[c];
    float var = ssum * (1.f / 1024.f) - (2.f * a - a * a) * m * m;
    float sc = gn3w[c] * rsqrtf(fmaxf(var, 0.f) + 1e-5f);
    normA[j * 64 + c] = sc;
    normB[j * 64 + c] = gn3b[c] - sc * a * m;
  }
}

// ---------------- gather + symmetric product + final dot ----------------
__global__ void k_final(const u16* __restrict__ Tg, const float* __restrict__ normA,
                        const float* __restrict__ normB, const int* __restrict__ pos,
                        const float* __restrict__ ldW, const float* __restrict__ ldb,
                        float* __restrict__ out) {
  int t = threadIdx.x, w = t >> 6, lane = t & 63;  // grid 2048 x 256, wave/pos
  int p = blockIdx.x * 4 + w;
  int i = pos[2 * p], j = pos[2 * p + 1];
  float t1 = bf2f(Tg[(size_t)lane * 1048576 + (size_t)i * 1024 + j]);
  float y1 = fmaxf(normA[j * 64 + lane] * t1 + normB[j * 64 + lane], 0.f);
  float t2 = bf2f(Tg[(size_t)lane * 1048576 + (size_t)j * 1024 + i]);
  float y2 = fmaxf(normA[i * 64 + lane] * t2 + normB[i * 64 + lane], 0.f);
  float z = y1 * y2 * ldW[lane];
#pragma unroll
  for (int off = 32; off > 0; off >>= 1) z += __shfl_down(z, off, 64);
  if (lane == 0) out[p] = z + ldb[0];
}

extern "C" void kernel_launch(void* const* d_in, const int* in_sizes, int n_in,
                              void* d_out, int out_size, void* d_ws, size_t ws_size,
                              hipStream_t stream) {
  const int* xids   = (const int*)d_in[0];
  const int* ei     = (const int*)d_in[1];
  const int* pos    = (const int*)d_in[2];
  const float* emb  = (const float*)d_in[3];
  const float* gW0  = (const float*)d_in[4];
  const float* gb0  = (const float*)d_in[5];
  const float* gnw0 = (const float*)d_in[6];
  const float* gnb0 = (const float*)d_in[7];
  const float* gna0 = (const float*)d_in[8];
  const float* gW1  = (const float*)d_in[9];
  const float* gb1  = (const float*)d_in[10];
  const float* gnw1 = (const float*)d_in[11];
  const float* gnb1 = (const float*)d_in[12];
  const float* gna1 = (const float*)d_in[13];
  const float* m1W  = (const float*)d_in[14];
  const float* m1b  = (const float*)d_in[15];
  const float* m2W  = (const float*)d_in[16];
  const float* m2b  = (const float*)d_in[17];
  const float* m3W  = (const float*)d_in[18];
  const float* m3b  = (const float*)d_in[19];
  const float* gn3w = (const float*)d_in[20];
  const float* gn3b = (const float*)d_in[21];
  const float* gn3a = (const float*)d_in[22];
  const float* ldW  = (const float*)d_in[23];
  const float* ldb  = (const float*)d_in[24];

  char* ws = (char*)d_ws;
  float* xf   = (float*)(ws + 0);
  float* h    = (float*)(ws + 262144);
  float* agg  = (float*)(ws + 524288);
  float* deg  = (float*)(ws + 786432);
  u16*   xb   = (u16*)(ws + 790528);
  unsigned char* eim = (unsigned char*)(ws + 921600);
  float* normA = (float*)(ws + 1970176);
  float* normB = (float*)(ws + 2232320);
  u16* x1tg = (u16*)(ws + 2494464);
  u16* x2tg = (u16*)(ws + 36048896);
  u16* prod = (u16*)(ws + 69603328);  // later overwritten in place by T
  float* out = (float*)d_out;

  k_setup<<<1024, 256, 0, stream>>>(xids, emb, xf, deg, (u32*)eim);
  k_edges<<<64, 256, 0, stream>>>(ei, deg, eim);
  // GCN layer 0
  k_gemm_node<<<1024, 64, 0, stream>>>(xf, gW0, gb0, deg, h, agg);
  k_agg<<<4096, 256, 0, stream>>>(ei, deg, h, agg);
  k_gnorm<<<64, 256, 0, stream>>>(agg, gnw0, gnb0, gna0, xf, xb, 0);
  // GCN layer 1
  k_gemm_node<<<1024, 64, 0, stream>>>(xf, gW1, gb1, deg, h, agg);
  k_agg<<<4096, 256, 0, stream>>>(ei, deg, h, agg);
  k_gnorm<<<64, 256, 0, stream>>>(agg, gnw1, gnb1, gna1, xf, xb, 1);
  // pairwise maps + batched 1024^3 GEMM, 4 channel-groups of 16
  for (int g = 0; g < 4; ++g) {
    k_build12<<<2048, 256, 0, stream>>>(xb, eim, m1W, m1b, m2W, m2b, x1tg, x2tg, g * 16);
    k_prodgemm<<<1024, 256, 0, stream>>>(x1tg, x2tg, prod, g * 16);
  }
  // T tensor (in place over prod) + stats + final
  k_buildT<<<1024, 256, 0, stream>>>(xb, eim, prod, m3W, m3b);
  k_stats<<<256, 1024, 0, stream>>>(prod, gn3w, gn3b, gn3a, normA, normB);
  k_final<<<2048, 256, 0, stream>>>(prod, normA, normB, pos, ldW, ldb, out);
}

// Round 5
// 604.096 us; speedup vs baseline: 1.0498x; 1.0498x over previous
//
#include <hip/hip_runtime.h>

// FWLNet: GCN x2 -> outer-product tensor -> two 65->64 maps -> 64x batched
// 1024^3 GEMM (prod) -> 129->64 map -> graph-norm(axis0) -> sym-product ->
// gather 8192 positions -> dot with ldW.
//
// R5 (from R4 pass @634us):
//  - k_prodgemm: glds (global_load_lds width=16) staging restored (m97
//    structure; R2's NaN was the input-dtype bug, not glds).
//  - k_buildT: x-part A-fragments read directly from global (identical
//    rounding, no LDS); prod-part staged conflict-free (uniform row,
//    lane-contiguous col -> 2-way = free). LDS 52.7KB -> ~33.5KB.
//
// ws layout (bytes):
//   0         xf    (1024x64 f32)
//   262144    h     (1024x64 f32)
//   524288    agg   (1024x64 f32)
//   786432    deg   (1024 f32)
//   790528    xb    (1024x64 bf16)
//   921600    eim   (1024x1024 u8)
//   1970176   normA (1024x64 f32)
//   2232320   normB (1024x64 f32)
//   2494464   x1tg  (16x1024x1024 bf16) = 33554432
//   36048896  x2tg  (16x1024x1024 bf16) = 33554432
//   69603328  prod/T(64x1024x1024 bf16) = 134217728
// total ~194.4 MB

typedef unsigned short u16;
typedef unsigned int u32;

#define DI static __device__ __forceinline__

DI float bf2f(u16 u) { union { u32 i; float f; } v; v.i = ((u32)u) << 16; return v.f; }
DI u16 f2bf(float f) {
  union { float f; u32 i; } v; v.f = f;
  u32 u = v.i;
  return (u16)((u + 0x7fffu + ((u >> 16) & 1u)) >> 16);
}

typedef __bf16 bf16x8 __attribute__((ext_vector_type(8)));
typedef float f32x4 __attribute__((ext_vector_type(4)));

#define MFMA16(a, b, c) __builtin_amdgcn_mfma_f32_16x16x32_bf16((a), (b), (c), 0, 0, 0)

typedef const __attribute__((address_space(1))) u32* gas1;
typedef __attribute__((address_space(3))) u32* las3;

// ---------------- node pipeline ----------------

__global__ void k_setup(const int* __restrict__ xids, const float* __restrict__ emb,
                        float* __restrict__ xf, float* __restrict__ deg,
                        u32* __restrict__ eimu) {
  int g = blockIdx.x * 256 + threadIdx.x;  // grid 1024
  if (g < 262144) eimu[g] = 0u;
  if (g < 1024) deg[g] = 1.0f;  // self-loop
  if (g < 65536) {
    int i = g >> 6, d = g & 63;
    xf[g] = emb[xids[i] * 64 + d];
  }
}

__global__ void k_edges(const int* __restrict__ ei, float* __restrict__ deg,
                        unsigned char* __restrict__ eim) {
  int e = blockIdx.x * 256 + threadIdx.x;  // grid 64
  if (e < 16384) {
    int s = ei[e], d = ei[16384 + e];
    atomicAdd(&deg[d], 1.0f);
    eim[s * 1024 + d] = 1;  // set semantics: duplicate writes benign
  }
}

// h = xf @ W;  agg = h/deg (self-loop) + gb
__global__ void k_gemm_node(const float* __restrict__ xf, const float* __restrict__ W,
                            const float* __restrict__ gb, const float* __restrict__ deg,
                            float* __restrict__ h, float* __restrict__ agg) {
  __shared__ float xrow[64];
  int i = blockIdx.x, c = threadIdx.x;  // grid 1024 x 64
  xrow[c] = xf[i * 64 + c];
  __syncthreads();
  float s = 0.f;
#pragma unroll
  for (int d = 0; d < 64; ++d) s += xrow[d] * W[d * 64 + c];
  h[i * 64 + c] = s;
  agg[i * 64 + c] = s / deg[i] + gb[c];
}

__global__ void k_agg(const int* __restrict__ ei, const float* __restrict__ deg,
                      const float* __restrict__ h, float* __restrict__ agg) {
  int g = blockIdx.x * 256 + threadIdx.x;  // grid 4096 -> e x c
  int e = g >> 6, c = g & 63;
  int s = ei[e], d = ei[16384 + e];
  float nrm = rsqrtf(deg[s]) * rsqrtf(deg[d]);
  atomicAdd(&agg[d * 64 + c], nrm * h[s * 64 + c]);
}

__global__ void k_gnorm(const float* __restrict__ agg, const float* __restrict__ gw,
                        const float* __restrict__ gbb, const float* __restrict__ ga,
                        float* __restrict__ xf, u16* __restrict__ xb, int last) {
  int c = blockIdx.x, t = threadIdx.x;  // grid 64 x 256
  float s = 0.f, ss = 0.f;
  for (int i = t; i < 1024; i += 256) {
    float v = agg[i * 64 + c];
    s += v; ss += v * v;
  }
  __shared__ float Ls[256], Lss[256];
  Ls[t] = s; Lss[t] = ss;
  __syncthreads();
  for (int off = 128; off > 0; off >>= 1) {
    if (t < off) { Ls[t] += Ls[t + off]; Lss[t] += Lss[t + off]; }
    __syncthreads();
  }
  float m = Ls[0] * (1.f / 1024.f);
  float a = ga[c];
  float var = Lss[0] * (1.f / 1024.f) - (2.f * a - a * a) * m * m;
  float sc = gw[c] * rsqrtf(fmaxf(var, 0.f) + 1e-5f);
  float bb = gbb[c];
  for (int i = t; i < 1024; i += 256) {
    float v = agg[i * 64 + c];
    float y = fmaxf(sc * (v - a * m) + bb, 0.f);
    xf[i * 64 + c] = y;
    if (last) xb[i * 64 + c] = f2bf(y);
  }
}

// ---------------- x1t / x2T builder (16 channels per launch) ----------------
// which=0: x1tg[cl][i][k] = relu( sum_d x[i,d]*m1W[d,c]*x[k,d] + eim[i,k]*m1W[64,c] + m1b[c] )
// which=1: x2tg[cl][j][k] = relu( sum_d x[j,d]*m2W[d,c]*x[k,d] + eim[k,j]*m2W[64,c] + m2b[c] )
__global__ __launch_bounds__(256, 2) void k_build12(
    const u16* __restrict__ xbg, const unsigned char* __restrict__ eim,
    const float* __restrict__ m1W, const float* __restrict__ m1b,
    const float* __restrict__ m2W, const float* __restrict__ m2b,
    u16* __restrict__ x1tg, u16* __restrict__ x2tg, int cbase) {
  __shared__ u16 As[128][80];  // pad 64->80 keeps 16B row alignment
  __shared__ u16 Bs[128][80];
  __shared__ unsigned char El[128][128];
  __shared__ float wsc[64];
  int b = blockIdx.x;  // grid 2048 = 2(which) x 64 tiles x 16 ch
  int cl = b & 15;
  int c = cbase + cl;
  int rest = b >> 4;
  int which = rest >> 6;
  int t6 = rest & 63;
  int rbase = (t6 >> 3) * 128, sbase = (t6 & 7) * 128;
  const float* W = which ? m2W : m1W;
  const float* bias = which ? m2b : m1b;
  u16* outp = (which ? x2tg : x1tg) + (size_t)cl * 1048576;
  int t = threadIdx.x;
  if (t < 64) wsc[t] = W[t * 64 + c];
  __syncthreads();
  {
    int row = t >> 1, half = t & 1;
    const u32* ga = (const u32*)(xbg + (rbase + row) * 64 + half * 32);
    u32* dstA = (u32*)&As[row][half * 32];
#pragma unroll
    for (int k = 0; k < 16; ++k) {
      u32 u = ga[k];
      float f0 = bf2f((u16)(u & 0xffffu)) * wsc[half * 32 + 2 * k];
      float f1 = bf2f((u16)(u >> 16)) * wsc[half * 32 + 2 * k + 1];
      dstA[k] = (u32)f2bf(f0) | ((u32)f2bf(f1) << 16);
    }
    const u32* gB = (const u32*)(xbg + (sbase + row) * 64 + half * 32);
    u32* dstB = (u32*)&Bs[row][half * 32];
#pragma unroll
    for (int k = 0; k < 16; ++k) dstB[k] = gB[k];
    int ab = which ? sbase : rbase;
    int bb = which ? rbase : sbase;
    const u32* gE = (const u32*)(eim + (size_t)(ab + row) * 1024 + bb + half * 64);
    u32* dstE = (u32*)&El[row][half * 64];
#pragma unroll
    for (int k = 0; k < 16; ++k) dstE[k] = gE[k];
  }
  __syncthreads();
  int lane = t & 63, w = t >> 6;
  int q = lane >> 4, r = lane & 15;
  int wr = w >> 1, wc = w & 1;
  f32x4 z4 = {0.f, 0.f, 0.f, 0.f};
  f32x4 acc[4][4];
#pragma unroll
  for (int mi = 0; mi < 4; ++mi)
#pragma unroll
    for (int ni = 0; ni < 4; ++ni) acc[mi][ni] = z4;
#pragma unroll
  for (int ks = 0; ks < 2; ++ks) {
    bf16x8 af[4], bfr[4];
#pragma unroll
    for (int mi = 0; mi < 4; ++mi)
      af[mi] = *(const bf16x8*)&As[wr * 64 + mi * 16 + r][ks * 32 + q * 8];
#pragma unroll
    for (int ni = 0; ni < 4; ++ni)
      bfr[ni] = *(const bf16x8*)&Bs[wc * 64 + ni * 16 + r][ks * 32 + q * 8];
#pragma unroll
    for (int mi = 0; mi < 4; ++mi)
#pragma unroll
      for (int ni = 0; ni < 4; ++ni) acc[mi][ni] = MFMA16(af[mi], bfr[ni], acc[mi][ni]);
  }
  float w64 = W[64 * 64 + c];
  float bsv = bias[c];
#pragma unroll
  for (int mi = 0; mi < 4; ++mi) {
#pragma unroll
    for (int ni = 0; ni < 4; ++ni) {
      int col = wc * 64 + ni * 16 + r;
#pragma unroll
      for (int tt = 0; tt < 4; ++tt) {
        int row2 = wr * 64 + mi * 16 + q * 4 + tt;
        float e = (float)(which ? El[col][row2] : El[row2][col]);
        float val = acc[mi][ni][tt] + e * w64 + bsv;
        outp[(size_t)(rbase + row2) * 1024 + (sbase + col)] = f2bf(fmaxf(val, 0.f));
      }
    }
  }
}

// ---------------- batched prod GEMM (16 channels per launch) ----------------
// prod[cbase+cl] = x1tg[cl] (MxK row-major) @ x2tg[cl]^T  (x2tg is B^T layout)
// m97 structure: global_load_lds width=16 staging.
__global__ __launch_bounds__(256, 2) void k_prodgemm(
    const u16* __restrict__ x1tg, const u16* __restrict__ x2tg,
    u16* __restrict__ prod, int cbase) {
  __shared__ u16 As[128 * 64];
  __shared__ u16 Bs[128 * 64];
  int b = blockIdx.x;  // grid 1024 = 64 tiles x 16 ch (cl in low bits)
  int cl = b & 15;
  int tile = b >> 4;
  int i0 = (tile >> 3) * 128, j0 = (tile & 7) * 128;
  const u16* Ap = x1tg + (size_t)cl * 1048576;
  const u16* Bp = x2tg + (size_t)cl * 1048576;
  u16* Pp = prod + (size_t)(cbase + cl) * 1048576;
  int t = threadIdx.x, lane = t & 63, w = t >> 6;
  int q = lane >> 4, r = lane & 15;
  int wr = w >> 1, wc = w & 1;
  int lrow = lane >> 3, lcol = (lane & 7) * 8;
  f32x4 z4 = {0.f, 0.f, 0.f, 0.f};
  f32x4 acc[4][4];
#pragma unroll
  for (int mi = 0; mi < 4; ++mi)
#pragma unroll
    for (int ni = 0; ni < 4; ++ni) acc[mi][ni] = z4;
  for (int kk = 0; kk < 1024; kk += 64) {
    __syncthreads();
#pragma unroll
    for (int s8 = 0; s8 < 4; ++s8) {
      int rowbase = w * 32 + s8 * 8;  // wave-uniform LDS base
      int grow = rowbase + lrow;      // 8 rows per glds (1KB/wave-inst)
      __builtin_amdgcn_global_load_lds(
          (gas1)(Ap + (size_t)(i0 + grow) * 1024 + kk + lcol),
          (las3)&As[rowbase * 64], 16, 0, 0);
      __builtin_amdgcn_global_load_lds(
          (gas1)(Bp + (size_t)(j0 + grow) * 1024 + kk + lcol),
          (las3)&Bs[rowbase * 64], 16, 0, 0);
    }
    __syncthreads();
#pragma unroll
    for (int ks = 0; ks < 2; ++ks) {
      bf16x8 af[4], bfr[4];
#pragma unroll
      for (int mi = 0; mi < 4; ++mi)
        af[mi] = *(const bf16x8*)&As[(wr * 64 + mi * 16 + r) * 64 + ks * 32 + q * 8];
#pragma unroll
      for (int ni = 0; ni < 4; ++ni)
        bfr[ni] = *(const bf16x8*)&Bs[(wc * 64 + ni * 16 + r) * 64 + ks * 32 + q * 8];
#pragma unroll
      for (int mi = 0; mi < 4; ++mi)
#pragma unroll
        for (int ni = 0; ni < 4; ++ni) acc[mi][ni] = MFMA16(af[mi], bfr[ni], acc[mi][ni]);
    }
  }
#pragma unroll
  for (int mi = 0; mi < 4; ++mi) {
#pragma unroll
    for (int ni = 0; ni < 4; ++ni) {
      int col = wc * 64 + ni * 16 + r;
#pragma unroll
      for (int tt = 0; tt < 4; ++tt) {
        int row2 = wr * 64 + mi * 16 + q * 4 + tt;
        Pp[(size_t)(i0 + row2) * 1024 + j0 + col] = f2bf(acc[mi][ni][tt]);
      }
    }
  }
}

// ---------------- T = [x_i*x_j | eim | prod] @ m3W + b3 (IN PLACE over prod) --
// one block per i. x-part A-fragments computed straight from global (bit-
// identical rounding to LDS path); prod-part staged in LDS with uniform-row,
// lane-contiguous-col writes (2-way bank = free). eim term in epilogue.
__global__ __launch_bounds__(256, 3) void k_buildT(
    const u16* __restrict__ xbg, const unsigned char* __restrict__ eim,
    u16* PT, const float* __restrict__ m3W, const float* __restrict__ m3b) {
  __shared__ u16 A2[128 * 64];  // prod part, [jloc][c], m97-style layout
  __shared__ u16 Wt[64][136];   // Wt[c][k]: k<64 -> m3W[k][c], k>=64 -> m3W[k+1][c]
  int i = blockIdx.x;  // grid 1024
  int t = threadIdx.x, lane = t & 63, w = t >> 6;
  int q = lane >> 4, r = lane & 15;
  {
    int row = t >> 1, half = t & 1;
    int rsrc = row < 64 ? row : row + 1;  // skip eim row 64
    const float4* gw = (const float4*)(m3W + rsrc * 64 + half * 32);
#pragma unroll
    for (int k = 0; k < 8; ++k) {
      float4 f = gw[k];
      Wt[half * 32 + 4 * k + 0][row] = f2bf(f.x);
      Wt[half * 32 + 4 * k + 1][row] = f2bf(f.y);
      Wt[half * 32 + 4 * k + 2][row] = f2bf(f.z);
      Wt[half * 32 + 4 * k + 3][row] = f2bf(f.w);
    }
  }
  // xi scale factors for this lane's q-slice (d = ks*32 + q*8 + e)
  float xif[2][8];
#pragma unroll
  for (int ks = 0; ks < 2; ++ks)
#pragma unroll
    for (int e = 0; e < 8; ++e) xif[ks][e] = bf2f(xbg[i * 64 + ks * 32 + q * 8 + e]);
  float w64c[4], b3c[4];
#pragma unroll
  for (int ni = 0; ni < 4; ++ni) {
    int cc = ni * 16 + r;
    w64c[ni] = m3W[64 * 64 + cc];
    b3c[ni] = m3b[cc];
  }
  int sc_ = t & 63;   // staging: plane (channel)
  int seg = t >> 6;   // staging: 32-j segment
  for (int jc = 0; jc < 8; ++jc) {
    int j0 = jc * 128;
    __syncthreads();  // prev-chunk A2 reads done (jc=0: orders Wt, harmless)
    {
      const u32* gp = (const u32*)(PT + (size_t)sc_ * 1048576 + (size_t)i * 1024 + j0 + seg * 32);
      u32 vals[16];
#pragma unroll
      for (int k = 0; k < 16; ++k) vals[k] = gp[k];
#pragma unroll
      for (int k = 0; k < 16; ++k) {
        A2[(seg * 32 + 2 * k) * 64 + sc_] = (u16)(vals[k] & 0xffffu);
        A2[(seg * 32 + 2 * k + 1) * 64 + sc_] = (u16)(vals[k] >> 16);
      }
    }
    __syncthreads();
    f32x4 z4 = {0.f, 0.f, 0.f, 0.f};
    f32x4 acc[2][4];
#pragma unroll
    for (int mi = 0; mi < 2; ++mi)
#pragma unroll
      for (int ni = 0; ni < 4; ++ni) acc[mi][ni] = z4;
    // k 0..63: x-pair part, fragments direct from global
#pragma unroll
    for (int ks = 0; ks < 2; ++ks) {
      bf16x8 af[2], bfr[4];
#pragma unroll
      for (int mi = 0; mi < 2; ++mi) {
        uint4 gx = *(const uint4*)&xbg[(j0 + w * 32 + mi * 16 + r) * 64 + ks * 32 + q * 8];
        u16 sa[8];
        u32 uu[4] = {gx.x, gx.y, gx.z, gx.w};
#pragma unroll
        for (int e = 0; e < 4; ++e) {
          sa[2 * e] = f2bf(bf2f((u16)(uu[e] & 0xffffu)) * xif[ks][2 * e]);
          sa[2 * e + 1] = f2bf(bf2f((u16)(uu[e] >> 16)) * xif[ks][2 * e + 1]);
        }
        af[mi] = *(const bf16x8*)sa;
      }
#pragma unroll
      for (int ni = 0; ni < 4; ++ni)
        bfr[ni] = *(const bf16x8*)&Wt[ni * 16 + r][ks * 32 + q * 8];
#pragma unroll
      for (int mi = 0; mi < 2; ++mi)
#pragma unroll
        for (int ni = 0; ni < 4; ++ni) acc[mi][ni] = MFMA16(af[mi], bfr[ni], acc[mi][ni]);
    }
    // k 64..127: prod part, fragments from LDS
#pragma unroll
    for (int ks = 2; ks < 4; ++ks) {
      bf16x8 af[2], bfr[4];
#pragma unroll
      for (int mi = 0; mi < 2; ++mi)
        af[mi] = *(const bf16x8*)&A2[(w * 32 + mi * 16 + r) * 64 + (ks - 2) * 32 + q * 8];
#pragma unroll
      for (int ni = 0; ni < 4; ++ni)
        bfr[ni] = *(const bf16x8*)&Wt[ni * 16 + r][ks * 32 + q * 8];
#pragma unroll
      for (int mi = 0; mi < 2; ++mi)
#pragma unroll
        for (int ni = 0; ni < 4; ++ni) acc[mi][ni] = MFMA16(af[mi], bfr[ni], acc[mi][ni]);
    }
#pragma unroll
    for (int mi = 0; mi < 2; ++mi) {
#pragma unroll
      for (int tt = 0; tt < 4; ++tt) {
        int jj = w * 32 + mi * 16 + q * 4 + tt;
        float ev = (float)eim[(size_t)i * 1024 + j0 + jj];
#pragma unroll
        for (int ni = 0; ni < 4; ++ni) {
          int cc = ni * 16 + r;
          float val = acc[mi][ni][tt] + ev * w64c[ni] + b3c[ni];
          PT[(size_t)cc * 1048576 + (size_t)i * 1024 + j0 + jj] = f2bf(val);
        }
      }
    }
  }
}

// ---------------- graph-norm stats over axis 0 (T layout [c][i][j]) ----------
__global__ void k_stats(const u16* __restrict__ Tg, const float* __restrict__ gn3w,
                        const float* __restrict__ gn3b, const float* __restrict__ gn3a,
                        float* __restrict__ normA, float* __restrict__ normB) {
  int b = blockIdx.x;  // grid 256 = 64 c x 4 j-chunks; block 1024 threads
  int c = b >> 2, jc = b & 3;
  int t = threadIdx.x;
  int jl = t & 255, seg = t >> 8;
  int j = jc * 256 + jl;
  const u16* base = Tg + (size_t)c * 1048576 + j;
  float s = 0.f, ss = 0.f;
#pragma unroll 4
  for (int i = seg * 256; i < seg * 256 + 256; ++i) {
    float v = bf2f(base[(size_t)i * 1024]);
    s += v; ss += v * v;
  }
  __shared__ float Ls[1024], Lss[1024];
  Ls[t] = s; Lss[t] = ss;
  __syncthreads();
  if (seg == 0) {
    float sum = Ls[jl] + Ls[jl + 256] + Ls[jl + 512] + Ls[jl + 768];
    float ssum = Lss[jl] + Lss[jl + 256] + Lss[jl + 512] + Lss[jl + 768];
    float m = sum * (1.f / 1024.f);
    float a = gn3a[c];
    float var = ssum * (1.f / 1024.f) - (2.f * a - a * a) * m * m;
    float sc = gn3w[c] * rsqrtf(fmaxf(var, 0.f) + 1e-5f);
    normA[j * 64 + c] = sc;
    normB[j * 64 + c] = gn3b[c] - sc * a * m;
  }
}

// ---------------- gather + symmetric product + final dot ----------------
__global__ void k_final(const u16* __restrict__ Tg, const float* __restrict__ normA,
                        const float* __restrict__ normB, const int* __restrict__ pos,
                        const float* __restrict__ ldW, const float* __restrict__ ldb,
                        float* __restrict__ out) {
  int t = threadIdx.x, w = t >> 6, lane = t & 63;  // grid 2048 x 256, wave/pos
  int p = blockIdx.x * 4 + w;
  int i = pos[2 * p], j = pos[2 * p + 1];
  float t1 = bf2f(Tg[(size_t)lane * 1048576 + (size_t)i * 1024 + j]);
  float y1 = fmaxf(normA[j * 64 + lane] * t1 + normB[j * 64 + lane], 0.f);
  float t2 = bf2f(Tg[(size_t)lane * 1048576 + (size_t)j * 1024 + i]);
  float y2 = fmaxf(normA[i * 64 + lane] * t2 + normB[i * 64 + lane], 0.f);
  float z = y1 * y2 * ldW[lane];
#pragma unroll
  for (int off = 32; off > 0; off >>= 1) z += __shfl_down(z, off, 64);
  if (lane == 0) out[p] = z + ldb[0];
}

extern "C" void kernel_launch(void* const* d_in, const int* in_sizes, int n_in,
                              void* d_out, int out_size, void* d_ws, size_t ws_size,
                              hipStream_t stream) {
  const int* xids   = (const int*)d_in[0];
  const int* ei     = (const int*)d_in[1];
  const int* pos    = (const int*)d_in[2];
  const float* emb  = (const float*)d_in[3];
  const float* gW0  = (const float*)d_in[4];
  const float* gb0  = (const float*)d_in[5];
  const float* gnw0 = (const float*)d_in[6];
  const float* gnb0 = (const float*)d_in[7];
  const float* gna0 = (const float*)d_in[8];
  const float* gW1  = (const float*)d_in[9];
  const float* gb1  = (const float*)d_in[10];
  const float* gnw1 = (const float*)d_in[11];
  const float* gnb1 = (const float*)d_in[12];
  const float* gna1 = (const float*)d_in[13];
  const float* m1W  = (const float*)d_in[14];
  const float* m1b  = (const float*)d_in[15];
  const float* m2W  = (const float*)d_in[16];
  const float* m2b  = (const float*)d_in[17];
  const float* m3W  = (const float*)d_in[18];
  const float* m3b  = (const float*)d_in[19];
  const float* gn3w = (const float*)d_in[20];
  const float* gn3b = (const float*)d_in[21];
  const float* gn3a = (const float*)d_in[22];
  const float* ldW  = (const float*)d_in[23];
  const float* ldb  = (const float*)d_in[24];

  char* ws = (char*)d_ws;
  float* xf   = (float*)(ws + 0);
  float* h    = (float*)(ws + 262144);
  float* agg  = (float*)(ws + 524288);
  float* deg  = (float*)(ws + 786432);
  u16*   xb   = (u16*)(ws + 790528);
  unsigned char* eim = (unsigned char*)(ws + 921600);
  float* normA = (float*)(ws + 1970176);
  float* normB = (float*)(ws + 2232320);
  u16* x1tg = (u16*)(ws + 2494464);
  u16* x2tg = (u16*)(ws + 36048896);
  u16* prod = (u16*)(ws + 69603328);  // later overwritten in place by T
  float* out = (float*)d_out;

  k_setup<<<1024, 256, 0, stream>>>(xids, emb, xf, deg, (u32*)eim);
  k_edges<<<64, 256, 0, stream>>>(ei, deg, eim);
  // GCN layer 0
  k_gemm_node<<<1024, 64, 0, stream>>>(xf, gW0, gb0, deg, h, agg);
  k_agg<<<4096, 256, 0, stream>>>(ei, deg, h, agg);
  k_gnorm<<<64, 256, 0, stream>>>(agg, gnw0, gnb0, gna0, xf, xb, 0);
  // GCN layer 1
  k_gemm_node<<<1024, 64, 0, stream>>>(xf, gW1, gb1, deg, h, agg);
  k_agg<<<4096, 256, 0, stream>>>(ei, deg, h, agg);
  k_gnorm<<<64, 256, 0, stream>>>(agg, gnw1, gnb1, gna1, xf, xb, 1);
  // pairwise maps + batched 1024^3 GEMM, 4 channel-groups of 16
  for (int g = 0; g < 4; ++g) {
    k_build12<<<2048, 256, 0, stream>>>(xb, eim, m1W, m1b, m2W, m2b, x1tg, x2tg, g * 16);
    k_prodgemm<<<1024, 256, 0, stream>>>(x1tg, x2tg, prod, g * 16);
  }
  // T tensor (in place over prod) + stats + final
  k_buildT<<<1024, 256, 0, stream>>>(xb, eim, prod, m3W, m3b);
  k_stats<<<256, 1024, 0, stream>>>(prod, gn3w, gn3b, gn3a, normA, normB);
  k_final<<<2048, 256, 0, stream>>>(prod, normA, normB, pos, ldW, ldb, out);
}

// Round 6
// 590.005 us; speedup vs baseline: 1.0749x; 1.0239x over previous
//
#include <hip/hip_runtime.h>

// FWLNet: GCN x2 -> outer-product tensor -> two 65->64 maps -> 64x batched
// 1024^3 GEMM (prod) -> 129->64 map -> graph-norm(axis0) -> sym-product ->
// gather 8192 positions -> dot with ldW.
//
// R6 (from R5 pass @604us):
//  - buildT: revert to R4 LDS-staged x-part (R5 direct-global frags regressed
//    77->96us); prod staging conflict-free (wave-uniform row, contiguous col);
//    launch_bounds(256,3); coalesced T stores via LDS transpose (aliased).
//  - prodgemm: coalesced C stores via LDS transpose (aliased over As/Bs).
//  - build12: El padded 132 (kills 16-way transposed read conflict);
//    coalesced stores via LDS transpose.
//
// ws layout unchanged (~194.4 MB): see R5.

typedef unsigned short u16;
typedef unsigned int u32;

#define DI static __device__ __forceinline__

DI float bf2f(u16 u) { union { u32 i; float f; } v; v.i = ((u32)u) << 16; return v.f; }
DI u16 f2bf(float f) {
  union { float f; u32 i; } v; v.f = f;
  u32 u = v.i;
  return (u16)((u + 0x7fffu + ((u >> 16) & 1u)) >> 16);
}

typedef __bf16 bf16x8 __attribute__((ext_vector_type(8)));
typedef float f32x4 __attribute__((ext_vector_type(4)));

#define MFMA16(a, b, c) __builtin_amdgcn_mfma_f32_16x16x32_bf16((a), (b), (c), 0, 0, 0)

typedef const __attribute__((address_space(1))) u32* gas1;
typedef __attribute__((address_space(3))) u32* las3;

// ---------------- node pipeline ----------------

__global__ void k_setup(const int* __restrict__ xids, const float* __restrict__ emb,
                        float* __restrict__ xf, float* __restrict__ deg,
                        u32* __restrict__ eimu) {
  int g = blockIdx.x * 256 + threadIdx.x;  // grid 1024
  if (g < 262144) eimu[g] = 0u;
  if (g < 1024) deg[g] = 1.0f;  // self-loop
  if (g < 65536) {
    int i = g >> 6, d = g & 63;
    xf[g] = emb[xids[i] * 64 + d];
  }
}

__global__ void k_edges(const int* __restrict__ ei, float* __restrict__ deg,
                        unsigned char* __restrict__ eim) {
  int e = blockIdx.x * 256 + threadIdx.x;  // grid 64
  if (e < 16384) {
    int s = ei[e], d = ei[16384 + e];
    atomicAdd(&deg[d], 1.0f);
    eim[s * 1024 + d] = 1;
  }
}

__global__ void k_gemm_node(const float* __restrict__ xf, const float* __restrict__ W,
                            const float* __restrict__ gb, const float* __restrict__ deg,
                            float* __restrict__ h, float* __restrict__ agg) {
  __shared__ float xrow[64];
  int i = blockIdx.x, c = threadIdx.x;  // grid 1024 x 64
  xrow[c] = xf[i * 64 + c];
  __syncthreads();
  float s = 0.f;
#pragma unroll
  for (int d = 0; d < 64; ++d) s += xrow[d] * W[d * 64 + c];
  h[i * 64 + c] = s;
  agg[i * 64 + c] = s / deg[i] + gb[c];
}

__global__ void k_agg(const int* __restrict__ ei, const float* __restrict__ deg,
                      const float* __restrict__ h, float* __restrict__ agg) {
  int g = blockIdx.x * 256 + threadIdx.x;  // grid 4096 -> e x c
  int e = g >> 6, c = g & 63;
  int s = ei[e], d = ei[16384 + e];
  float nrm = rsqrtf(deg[s]) * rsqrtf(deg[d]);
  atomicAdd(&agg[d * 64 + c], nrm * h[s * 64 + c]);
}

__global__ void k_gnorm(const float* __restrict__ agg, const float* __restrict__ gw,
                        const float* __restrict__ gbb, const float* __restrict__ ga,
                        float* __restrict__ xf, u16* __restrict__ xb, int last) {
  int c = blockIdx.x, t = threadIdx.x;  // grid 64 x 256
  float s = 0.f, ss = 0.f;
  for (int i = t; i < 1024; i += 256) {
    float v = agg[i * 64 + c];
    s += v; ss += v * v;
  }
  __shared__ float Ls[256], Lss[256];
  Ls[t] = s; Lss[t] = ss;
  __syncthreads();
  for (int off = 128; off > 0; off >>= 1) {
    if (t < off) { Ls[t] += Ls[t + off]; Lss[t] += Lss[t + off]; }
    __syncthreads();
  }
  float m = Ls[0] * (1.f / 1024.f);
  float a = ga[c];
  float var = Lss[0] * (1.f / 1024.f) - (2.f * a - a * a) * m * m;
  float sc = gw[c] * rsqrtf(fmaxf(var, 0.f) + 1e-5f);
  float bb = gbb[c];
  for (int i = t; i < 1024; i += 256) {
    float v = agg[i * 64 + c];
    float y = fmaxf(sc * (v - a * m) + bb, 0.f);
    xf[i * 64 + c] = y;
    if (last) xb[i * 64 + c] = f2bf(y);
  }
}

// ---------------- x1t / x2T builder (16 channels per launch) ----------------
__global__ __launch_bounds__(256, 2) void k_build12(
    const u16* __restrict__ xbg, const unsigned char* __restrict__ eim,
    const float* __restrict__ m1W, const float* __restrict__ m1b,
    const float* __restrict__ m2W, const float* __restrict__ m2b,
    u16* __restrict__ x1tg, u16* __restrict__ x2tg, int cbase) {
  // pool: As[128][80] (0..10239) | Bs[128][80] (10240..20479); Cs aliases 0..17407
  __shared__ u16 pool[20480];
  __shared__ unsigned char El[128 * 132];  // pad 132: transposed reads ~2-way
  __shared__ float wsc[64];
  int b = blockIdx.x;  // grid 2048 = 2(which) x 64 tiles x 16 ch
  int cl = b & 15;
  int c = cbase + cl;
  int rest = b >> 4;
  int which = rest >> 6;
  int t6 = rest & 63;
  int rbase = (t6 >> 3) * 128, sbase = (t6 & 7) * 128;
  const float* W = which ? m2W : m1W;
  const float* bias = which ? m2b : m1b;
  u16* outp = (which ? x2tg : x1tg) + (size_t)cl * 1048576;
  int t = threadIdx.x;
  if (t < 64) wsc[t] = W[t * 64 + c];
  __syncthreads();
  {
    int row = t >> 1, half = t & 1;
    const u32* ga = (const u32*)(xbg + (rbase + row) * 64 + half * 32);
    u32* dstA = (u32*)&pool[row * 80 + half * 32];
#pragma unroll
    for (int k = 0; k < 16; ++k) {
      u32 u = ga[k];
      float f0 = bf2f((u16)(u & 0xffffu)) * wsc[half * 32 + 2 * k];
      float f1 = bf2f((u16)(u >> 16)) * wsc[half * 32 + 2 * k + 1];
      dstA[k] = (u32)f2bf(f0) | ((u32)f2bf(f1) << 16);
    }
    const u32* gB = (const u32*)(xbg + (sbase + row) * 64 + half * 32);
    u32* dstB = (u32*)&pool[10240 + row * 80 + half * 32];
#pragma unroll
    for (int k = 0; k < 16; ++k) dstB[k] = gB[k];
    int ab = which ? sbase : rbase;
    int bb = which ? rbase : sbase;
    const u32* gE = (const u32*)(eim + (size_t)(ab + row) * 1024 + bb + half * 64);
    u32* dstE = (u32*)&El[row * 132 + half * 64];
#pragma unroll
    for (int k = 0; k < 16; ++k) dstE[k] = gE[k];
  }
  __syncthreads();
  int lane = t & 63, w = t >> 6;
  int q = lane >> 4, r = lane & 15;
  int wr = w >> 1, wc = w & 1;
  f32x4 z4 = {0.f, 0.f, 0.f, 0.f};
  f32x4 acc[4][4];
#pragma unroll
  for (int mi = 0; mi < 4; ++mi)
#pragma unroll
    for (int ni = 0; ni < 4; ++ni) acc[mi][ni] = z4;
#pragma unroll
  for (int ks = 0; ks < 2; ++ks) {
    bf16x8 af[4], bfr[4];
#pragma unroll
    for (int mi = 0; mi < 4; ++mi)
      af[mi] = *(const bf16x8*)&pool[(wr * 64 + mi * 16 + r) * 80 + ks * 32 + q * 8];
#pragma unroll
    for (int ni = 0; ni < 4; ++ni)
      bfr[ni] = *(const bf16x8*)&pool[10240 + (wc * 64 + ni * 16 + r) * 80 + ks * 32 + q * 8];
#pragma unroll
    for (int mi = 0; mi < 4; ++mi)
#pragma unroll
      for (int ni = 0; ni < 4; ++ni) acc[mi][ni] = MFMA16(af[mi], bfr[ni], acc[mi][ni]);
  }
  float w64 = W[64 * 64 + c];
  float bsv = bias[c];
  // finalize values in registers (El reads before Cs overwrites pool)
#pragma unroll
  for (int mi = 0; mi < 4; ++mi) {
#pragma unroll
    for (int ni = 0; ni < 4; ++ni) {
      int col = wc * 64 + ni * 16 + r;
#pragma unroll
      for (int tt = 0; tt < 4; ++tt) {
        int row2 = wr * 64 + mi * 16 + q * 4 + tt;
        float e = (float)(which ? El[col * 132 + row2] : El[row2 * 132 + col]);
        acc[mi][ni][tt] = fmaxf(acc[mi][ni][tt] + e * w64 + bsv, 0.f);
      }
    }
  }
  __syncthreads();  // all frag reads of pool done
  // Cs transpose: stride 136 (16B-aligned rows, spread banks)
#pragma unroll
  for (int mi = 0; mi < 4; ++mi)
#pragma unroll
    for (int ni = 0; ni < 4; ++ni) {
      int col = wc * 64 + ni * 16 + r;
#pragma unroll
      for (int tt = 0; tt < 4; ++tt) {
        int row2 = wr * 64 + mi * 16 + q * 4 + tt;
        pool[row2 * 136 + col] = f2bf(acc[mi][ni][tt]);
      }
    }
  __syncthreads();
  {
    int rseg = t >> 4, cseg = t & 15;
#pragma unroll
    for (int it = 0; it < 8; ++it) {
      int row = it * 16 + rseg;
      uint4 v = *(const uint4*)&pool[row * 136 + cseg * 8];
      *(uint4*)(outp + (size_t)(rbase + row) * 1024 + sbase + cseg * 8) = v;
    }
  }
}

// ---------------- batched prod GEMM (16 channels per launch) ----------------
// prod[cbase+cl] = x1tg[cl] @ x2tg[cl]^T ; m97 glds staging; coalesced C store.
__global__ __launch_bounds__(256, 3) void k_prodgemm(
    const u16* __restrict__ x1tg, const u16* __restrict__ x2tg,
    u16* __restrict__ prod, int cbase) {
  // pool: As (0..8191) | Bs (8192..16383); Cs aliases 0..17407 (stride 136)
  __shared__ u16 pool[17408];
  int b = blockIdx.x;  // grid 1024 = 64 tiles x 16 ch (cl low bits)
  int cl = b & 15;
  int tile = b >> 4;
  int i0 = (tile >> 3) * 128, j0 = (tile & 7) * 128;
  const u16* Ap = x1tg + (size_t)cl * 1048576;
  const u16* Bp = x2tg + (size_t)cl * 1048576;
  u16* Pp = prod + (size_t)(cbase + cl) * 1048576;
  int t = threadIdx.x, lane = t & 63, w = t >> 6;
  int q = lane >> 4, r = lane & 15;
  int wr = w >> 1, wc = w & 1;
  int lrow = lane >> 3, lcol = (lane & 7) * 8;
  f32x4 z4 = {0.f, 0.f, 0.f, 0.f};
  f32x4 acc[4][4];
#pragma unroll
  for (int mi = 0; mi < 4; ++mi)
#pragma unroll
    for (int ni = 0; ni < 4; ++ni) acc[mi][ni] = z4;
  for (int kk = 0; kk < 1024; kk += 64) {
    __syncthreads();
#pragma unroll
    for (int s8 = 0; s8 < 4; ++s8) {
      int rowbase = w * 32 + s8 * 8;  // wave-uniform LDS base
      int grow = rowbase + lrow;
      __builtin_amdgcn_global_load_lds(
          (gas1)(Ap + (size_t)(i0 + grow) * 1024 + kk + lcol),
          (las3)&pool[rowbase * 64], 16, 0, 0);
      __builtin_amdgcn_global_load_lds(
          (gas1)(Bp + (size_t)(j0 + grow) * 1024 + kk + lcol),
          (las3)&pool[8192 + rowbase * 64], 16, 0, 0);
    }
    __syncthreads();
#pragma unroll
    for (int ks = 0; ks < 2; ++ks) {
      bf16x8 af[4], bfr[4];
#pragma unroll
      for (int mi = 0; mi < 4; ++mi)
        af[mi] = *(const bf16x8*)&pool[(wr * 64 + mi * 16 + r) * 64 + ks * 32 + q * 8];
#pragma unroll
      for (int ni = 0; ni < 4; ++ni)
        bfr[ni] = *(const bf16x8*)&pool[8192 + (wc * 64 + ni * 16 + r) * 64 + ks * 32 + q * 8];
#pragma unroll
      for (int mi = 0; mi < 4; ++mi)
#pragma unroll
        for (int ni = 0; ni < 4; ++ni) acc[mi][ni] = MFMA16(af[mi], bfr[ni], acc[mi][ni]);
    }
  }
  __syncthreads();  // frag reads done before Cs overwrite
#pragma unroll
  for (int mi = 0; mi < 4; ++mi)
#pragma unroll
    for (int ni = 0; ni < 4; ++ni) {
      int col = wc * 64 + ni * 16 + r;
#pragma unroll
      for (int tt = 0; tt < 4; ++tt) {
        int row2 = wr * 64 + mi * 16 + q * 4 + tt;
        pool[row2 * 136 + col] = f2bf(acc[mi][ni][tt]);
      }
    }
  __syncthreads();
  {
    int rseg = t >> 4, cseg = t & 15;
#pragma unroll
    for (int it = 0; it < 8; ++it) {
      int row = it * 16 + rseg;
      uint4 v = *(const uint4*)&pool[row * 136 + cseg * 8];
      *(uint4*)(Pp + (size_t)(i0 + row) * 1024 + j0 + cseg * 8) = v;
    }
  }
}

// ---------------- T = [x_i*x_j | eim | prod] @ m3W + b3 (IN PLACE over prod) --
// R4 structure (LDS-staged x-part) + conflict-free prod staging + 3 blocks/CU
// + coalesced T stores via LDS transpose (Cs aliases A).
__global__ __launch_bounds__(256, 3) void k_buildT(
    const u16* __restrict__ xbg, const unsigned char* __restrict__ eim,
    u16* PT, const float* __restrict__ m3W, const float* __restrict__ m3b) {
  __shared__ u16 A[128 * 136];  // [j][k]: k<64 x-part, k>=64 prod-part; Cs alias
  __shared__ u16 Wt[64 * 136];  // Wt[c][k]: k<64 -> m3W[k][c], k>=64 -> m3W[k+1][c]
  __shared__ float xi[64];
  int i = blockIdx.x;  // grid 1024
  int t = threadIdx.x, lane = t & 63, w = t >> 6;
  int q = lane >> 4, r = lane & 15;
  if (t < 64) xi[t] = bf2f(xbg[i * 64 + t]);
  {
    int row = t >> 1, half = t & 1;
    int rsrc = row < 64 ? row : row + 1;  // skip eim row 64
    const float4* gw = (const float4*)(m3W + rsrc * 64 + half * 32);
#pragma unroll
    for (int k = 0; k < 8; ++k) {
      float4 f = gw[k];
      Wt[(half * 32 + 4 * k + 0) * 136 + row] = f2bf(f.x);
      Wt[(half * 32 + 4 * k + 1) * 136 + row] = f2bf(f.y);
      Wt[(half * 32 + 4 * k + 2) * 136 + row] = f2bf(f.z);
      Wt[(half * 32 + 4 * k + 3) * 136 + row] = f2bf(f.w);
    }
  }
  float w64c[4], b3c[4];
#pragma unroll
  for (int ni = 0; ni < 4; ++ni) {
    int cc = ni * 16 + r;
    w64c[ni] = m3W[64 * 64 + cc];
    b3c[ni] = m3b[cc];
  }
  int sc_ = t & 63;   // prod staging: channel plane
  int seg = t >> 6;   // prod staging: 32-j segment (wave-uniform)
  for (int jc = 0; jc < 8; ++jc) {
    int j0 = jc * 128;
    __syncthreads();  // prior Cs reads done; (jc=0) orders Wt/xi
    {
      // x-part: A[jj][0..63] = x[j0+jj,:] * x[i,:]
      int jj = t >> 1, half = t & 1;
      const u32* gx = (const u32*)(xbg + (j0 + jj) * 64 + half * 32);
      u32* dst = (u32*)&A[jj * 136 + half * 32];
#pragma unroll
      for (int k = 0; k < 16; ++k) {
        u32 u = gx[k];
        float f0 = bf2f((u16)(u & 0xffffu)) * xi[half * 32 + 2 * k];
        float f1 = bf2f((u16)(u >> 16)) * xi[half * 32 + 2 * k + 1];
        dst[k] = (u32)f2bf(f0) | ((u32)f2bf(f1) << 16);
      }
      // prod-part: A[jj][64+c] = prod[c][i][j0+jj]; conflict-free writes
      const uint4* gp = (const uint4*)(PT + (size_t)sc_ * 1048576 + (size_t)i * 1024 + j0 + seg * 32);
      uint4 v[4];
#pragma unroll
      for (int k4 = 0; k4 < 4; ++k4) v[k4] = gp[k4];
#pragma unroll
      for (int k4 = 0; k4 < 4; ++k4) {
        u32 uu[4] = {v[k4].x, v[k4].y, v[k4].z, v[k4].w};
#pragma unroll
        for (int e = 0; e < 4; ++e) {
          int jrow = seg * 32 + k4 * 8 + 2 * e;
          A[jrow * 136 + 64 + sc_] = (u16)(uu[e] & 0xffffu);
          A[(jrow + 1) * 136 + 64 + sc_] = (u16)(uu[e] >> 16);
        }
      }
    }
    __syncthreads();
    f32x4 z4 = {0.f, 0.f, 0.f, 0.f};
    f32x4 acc[2][4];
#pragma unroll
    for (int mi = 0; mi < 2; ++mi)
#pragma unroll
      for (int ni = 0; ni < 4; ++ni) acc[mi][ni] = z4;
#pragma unroll
    for (int ks = 0; ks < 4; ++ks) {
      bf16x8 af[2], bfr[4];
#pragma unroll
      for (int mi = 0; mi < 2; ++mi)
        af[mi] = *(const bf16x8*)&A[(w * 32 + mi * 16 + r) * 136 + ks * 32 + q * 8];
#pragma unroll
      for (int ni = 0; ni < 4; ++ni)
        bfr[ni] = *(const bf16x8*)&Wt[(ni * 16 + r) * 136 + ks * 32 + q * 8];
#pragma unroll
      for (int mi = 0; mi < 2; ++mi)
#pragma unroll
        for (int ni = 0; ni < 4; ++ni) acc[mi][ni] = MFMA16(af[mi], bfr[ni], acc[mi][ni]);
    }
    // finalize values in registers
#pragma unroll
    for (int mi = 0; mi < 2; ++mi) {
#pragma unroll
      for (int tt = 0; tt < 4; ++tt) {
        int jj = w * 32 + mi * 16 + q * 4 + tt;
        float ev = (float)eim[(size_t)i * 1024 + j0 + jj];
#pragma unroll
        for (int ni = 0; ni < 4; ++ni)
          acc[mi][ni][tt] = acc[mi][ni][tt] + ev * w64c[ni] + b3c[ni];
      }
    }
    __syncthreads();  // all frag reads of A done before Cs overwrite
    // Cs[cc][jj], stride 136; then coalesced store of T[cc][i][j0..]
#pragma unroll
    for (int mi = 0; mi < 2; ++mi)
#pragma unroll
      for (int ni = 0; ni < 4; ++ni) {
        int cc = ni * 16 + r;
#pragma unroll
        for (int tt = 0; tt < 4; ++tt) {
          int jj = w * 32 + mi * 16 + q * 4 + tt;
          A[cc * 136 + jj] = f2bf(acc[mi][ni][tt]);
        }
      }
    __syncthreads();
    {
      int cc2 = t >> 2, q64 = t & 3;
#pragma unroll
      for (int k = 0; k < 4; ++k) {
        uint4 v = *(const uint4*)&A[cc2 * 136 + q64 * 32 + k * 8];
        *(uint4*)(PT + (size_t)cc2 * 1048576 + (size_t)i * 1024 + j0 + q64 * 32 + k * 8) = v;
      }
    }
  }
}

// ---------------- graph-norm stats over axis 0 (T layout [c][i][j]) ----------
__global__ void k_stats(const u16* __restrict__ Tg, const float* __restrict__ gn3w,
                        const float* __restrict__ gn3b, const float* __restrict__ gn3a,
                        float* __restrict__ normA, float* __restrict__ normB) {
  int b = blockIdx.x;  // grid 256 = 64 c x 4 j-chunks; block 1024 threads
  int c = b >> 2, jc = b & 3;
  int t = threadIdx.x;
  int jl = t & 255, seg = t >> 8;
  int j = jc * 256 + jl;
  const u16* base = Tg + (size_t)c * 1048576 + j;
  float s = 0.f, ss = 0.f;
#pragma unroll 4
  for (int i = seg * 256; i < seg * 256 + 256; ++i) {
    float v = bf2f(base[(size_t)i * 1024]);
    s += v; ss += v * v;
  }
  __shared__ float Ls[1024], Lss[1024];
  Ls[t] = s; Lss[t] = ss;
  __syncthreads();
  if (seg == 0) {
    float sum = Ls[jl] + Ls[jl + 256] + Ls[jl + 512] + Ls[jl + 768];
    float ssum = Lss[jl] + Lss[jl + 256] + Lss[jl + 512] + Lss[jl + 768];
    float m = sum * (1.f / 1024.f);
    float a = gn3a[c];
    float var = ssum * (1.f / 1024.f) - (2.f * a - a * a) * m * m;
    float sc = gn3w[c] * rsqrtf(fmaxf(var, 0.f) + 1e-5f);
    normA[j * 64 + c] = sc;
    normB[j * 64 + c] = gn3b[c] - sc * a * m;
  }
}

// ---------------- gather + symmetric product + final dot ----------------
__global__ void k_final(const u16* __restrict__ Tg, const float* __restrict__ normA,
                        const float* __restrict__ normB, const int* __restrict__ pos,
                        const float* __restrict__ ldW, const float* __restrict__ ldb,
                        float* __restrict__ out) {
  int t = threadIdx.x, w = t >> 6, lane = t & 63;  // grid 2048 x 256, wave/pos
  int p = blockIdx.x * 4 + w;
  int i = pos[2 * p], j = pos[2 * p + 1];
  float t1 = bf2f(Tg[(size_t)lane * 1048576 + (size_t)i * 1024 + j]);
  float y1 = fmaxf(normA[j * 64 + lane] * t1 + normB[j * 64 + lane], 0.f);
  float t2 = bf2f(Tg[(size_t)lane * 1048576 + (size_t)j * 1024 + i]);
  float y2 = fmaxf(normA[i * 64 + lane] * t2 + normB[i * 64 + lane], 0.f);
  float z = y1 * y2 * ldW[lane];
#pragma unroll
  for (int off = 32; off > 0; off >>= 1) z += __shfl_down(z, off, 64);
  if (lane == 0) out[p] = z + ldb[0];
}

extern "C" void kernel_launch(void* const* d_in, const int* in_sizes, int n_in,
                              void* d_out, int out_size, void* d_ws, size_t ws_size,
                              hipStream_t stream) {
  const int* xids   = (const int*)d_in[0];
  const int* ei     = (const int*)d_in[1];
  const int* pos    = (const int*)d_in[2];
  const float* emb  = (const float*)d_in[3];
  const float* gW0  = (const float*)d_in[4];
  const float* gb0  = (const float*)d_in[5];
  const float* gnw0 = (const float*)d_in[6];
  const float* gnb0 = (const float*)d_in[7];
  const float* gna0 = (const float*)d_in[8];
  const float* gW1  = (const float*)d_in[9];
  const float* gb1  = (const float*)d_in[10];
  const float* gnw1 = (const float*)d_in[11];
  const float* gnb1 = (const float*)d_in[12];
  const float* gna1 = (const float*)d_in[13];
  const float* m1W  = (const float*)d_in[14];
  const float* m1b  = (const float*)d_in[15];
  const float* m2W  = (const float*)d_in[16];
  const float* m2b  = (const float*)d_in[17];
  const float* m3W  = (const float*)d_in[18];
  const float* m3b  = (const float*)d_in[19];
  const float* gn3w = (const float*)d_in[20];
  const float* gn3b = (const float*)d_in[21];
  const float* gn3a = (const float*)d_in[22];
  const float* ldW  = (const float*)d_in[23];
  const float* ldb  = (const float*)d_in[24];

  char* ws = (char*)d_ws;
  float* xf   = (float*)(ws + 0);
  float* h    = (float*)(ws + 262144);
  float* agg  = (float*)(ws + 524288);
  float* deg  = (float*)(ws + 786432);
  u16*   xb   = (u16*)(ws + 790528);
  unsigned char* eim = (unsigned char*)(ws + 921600);
  float* normA = (float*)(ws + 1970176);
  float* normB = (float*)(ws + 2232320);
  u16* x1tg = (u16*)(ws + 2494464);
  u16* x2tg = (u16*)(ws + 36048896);
  u16* prod = (u16*)(ws + 69603328);  // later overwritten in place by T
  float* out = (float*)d_out;

  k_setup<<<1024, 256, 0, stream>>>(xids, emb, xf, deg, (u32*)eim);
  k_edges<<<64, 256, 0, stream>>>(ei, deg, eim);
  // GCN layer 0
  k_gemm_node<<<1024, 64, 0, stream>>>(xf, gW0, gb0, deg, h, agg);
  k_agg<<<4096, 256, 0, stream>>>(ei, deg, h, agg);
  k_gnorm<<<64, 256, 0, stream>>>(agg, gnw0, gnb0, gna0, xf, xb, 0);
  // GCN layer 1
  k_gemm_node<<<1024, 64, 0, stream>>>(xf, gW1, gb1, deg, h, agg);
  k_agg<<<4096, 256, 0, stream>>>(ei, deg, h, agg);
  k_gnorm<<<64, 256, 0, stream>>>(agg, gnw1, gnb1, gna1, xf, xb, 1);
  // pairwise maps + batched 1024^3 GEMM, 4 channel-groups of 16
  for (int g = 0; g < 4; ++g) {
    k_build12<<<2048, 256, 0, stream>>>(xb, eim, m1W, m1b, m2W, m2b, x1tg, x2tg, g * 16);
    k_prodgemm<<<1024, 256, 0, stream>>>(x1tg, x2tg, prod, g * 16);
  }
  // T tensor (in place over prod) + stats + final
  k_buildT<<<1024, 256, 0, stream>>>(xb, eim, prod, m3W, m3b);
  k_stats<<<256, 1024, 0, stream>>>(prod, gn3w, gn3b, gn3a, normA, normB);
  k_final<<<2048, 256, 0, stream>>>(prod, normA, normB, pos, ldW, ldb, out);
}

// Round 7
// 587.718 us; speedup vs baseline: 1.0791x; 1.0039x over previous
//
#include <hip/hip_runtime.h>

// FWLNet: GCN x2 -> outer-product tensor -> two 65->64 maps -> 64x batched
// 1024^3 GEMM (prod) -> 129->64 map -> graph-norm(axis0) -> sym-product ->
// gather 8192 positions -> dot with ldW.
//
// R7 (from R6 pass @590us):
//  - k_stats: coalesced row reads (was 2KB-strided, ~32x line amplification)
//    + f32 atomic partials into S/SS (overlaid on dead x1tg, zeroed by
//    buildT's prologue) + tiny finalize kernel.
//  - k_buildT: prod staging via coalesced-global -> LDS scratch bounce
//    (4 lanes/plane, 256B contiguous; scratch stride 130 -> 2-way free both
//    directions). Was: 64 lanes -> 64 distinct 1MB-strided lines per inst.
//
// ws layout unchanged (~194.4 MB): see R5/R6.

typedef unsigned short u16;
typedef unsigned int u32;

#define DI static __device__ __forceinline__

DI float bf2f(u16 u) { union { u32 i; float f; } v; v.i = ((u32)u) << 16; return v.f; }
DI u16 f2bf(float f) {
  union { float f; u32 i; } v; v.f = f;
  u32 u = v.i;
  return (u16)((u + 0x7fffu + ((u >> 16) & 1u)) >> 16);
}

typedef __bf16 bf16x8 __attribute__((ext_vector_type(8)));
typedef float f32x4 __attribute__((ext_vector_type(4)));

#define MFMA16(a, b, c) __builtin_amdgcn_mfma_f32_16x16x32_bf16((a), (b), (c), 0, 0, 0)

typedef const __attribute__((address_space(1))) u32* gas1;
typedef __attribute__((address_space(3))) u32* las3;

// ---------------- node pipeline ----------------

__global__ void k_setup(const int* __restrict__ xids, const float* __restrict__ emb,
                        float* __restrict__ xf, float* __restrict__ deg,
                        u32* __restrict__ eimu) {
  int g = blockIdx.x * 256 + threadIdx.x;  // grid 1024
  if (g < 262144) eimu[g] = 0u;
  if (g < 1024) deg[g] = 1.0f;  // self-loop
  if (g < 65536) {
    int i = g >> 6, d = g & 63;
    xf[g] = emb[xids[i] * 64 + d];
  }
}

__global__ void k_edges(const int* __restrict__ ei, float* __restrict__ deg,
                        unsigned char* __restrict__ eim) {
  int e = blockIdx.x * 256 + threadIdx.x;  // grid 64
  if (e < 16384) {
    int s = ei[e], d = ei[16384 + e];
    atomicAdd(&deg[d], 1.0f);
    eim[s * 1024 + d] = 1;
  }
}

__global__ void k_gemm_node(const float* __restrict__ xf, const float* __restrict__ W,
                            const float* __restrict__ gb, const float* __restrict__ deg,
                            float* __restrict__ h, float* __restrict__ agg) {
  __shared__ float xrow[64];
  int i = blockIdx.x, c = threadIdx.x;  // grid 1024 x 64
  xrow[c] = xf[i * 64 + c];
  __syncthreads();
  float s = 0.f;
#pragma unroll
  for (int d = 0; d < 64; ++d) s += xrow[d] * W[d * 64 + c];
  h[i * 64 + c] = s;
  agg[i * 64 + c] = s / deg[i] + gb[c];
}

__global__ void k_agg(const int* __restrict__ ei, const float* __restrict__ deg,
                      const float* __restrict__ h, float* __restrict__ agg) {
  int g = blockIdx.x * 256 + threadIdx.x;  // grid 4096 -> e x c
  int e = g >> 6, c = g & 63;
  int s = ei[e], d = ei[16384 + e];
  float nrm = rsqrtf(deg[s]) * rsqrtf(deg[d]);
  atomicAdd(&agg[d * 64 + c], nrm * h[s * 64 + c]);
}

__global__ void k_gnorm(const float* __restrict__ agg, const float* __restrict__ gw,
                        const float* __restrict__ gbb, const float* __restrict__ ga,
                        float* __restrict__ xf, u16* __restrict__ xb, int last) {
  int c = blockIdx.x, t = threadIdx.x;  // grid 64 x 256
  float s = 0.f, ss = 0.f;
  for (int i = t; i < 1024; i += 256) {
    float v = agg[i * 64 + c];
    s += v; ss += v * v;
  }
  __shared__ float Ls[256], Lss[256];
  Ls[t] = s; Lss[t] = ss;
  __syncthreads();
  for (int off = 128; off > 0; off >>= 1) {
    if (t < off) { Ls[t] += Ls[t + off]; Lss[t] += Lss[t + off]; }
    __syncthreads();
  }
  float m = Ls[0] * (1.f / 1024.f);
  float a = ga[c];
  float var = Lss[0] * (1.f / 1024.f) - (2.f * a - a * a) * m * m;
  float sc = gw[c] * rsqrtf(fmaxf(var, 0.f) + 1e-5f);
  float bb = gbb[c];
  for (int i = t; i < 1024; i += 256) {
    float v = agg[i * 64 + c];
    float y = fmaxf(sc * (v - a * m) + bb, 0.f);
    xf[i * 64 + c] = y;
    if (last) xb[i * 64 + c] = f2bf(y);
  }
}

// ---------------- x1t / x2T builder (16 channels per launch) ----------------
__global__ __launch_bounds__(256, 2) void k_build12(
    const u16* __restrict__ xbg, const unsigned char* __restrict__ eim,
    const float* __restrict__ m1W, const float* __restrict__ m1b,
    const float* __restrict__ m2W, const float* __restrict__ m2b,
    u16* __restrict__ x1tg, u16* __restrict__ x2tg, int cbase) {
  // pool: As[128][80] (0..10239) | Bs[128][80] (10240..20479); Cs aliases 0..17407
  __shared__ u16 pool[20480];
  __shared__ unsigned char El[128 * 132];  // pad 132: transposed reads ~2-way
  __shared__ float wsc[64];
  int b = blockIdx.x;  // grid 2048 = 2(which) x 64 tiles x 16 ch
  int cl = b & 15;
  int c = cbase + cl;
  int rest = b >> 4;
  int which = rest >> 6;
  int t6 = rest & 63;
  int rbase = (t6 >> 3) * 128, sbase = (t6 & 7) * 128;
  const float* W = which ? m2W : m1W;
  const float* bias = which ? m2b : m1b;
  u16* outp = (which ? x2tg : x1tg) + (size_t)cl * 1048576;
  int t = threadIdx.x;
  if (t < 64) wsc[t] = W[t * 64 + c];
  __syncthreads();
  {
    int row = t >> 1, half = t & 1;
    const u32* ga = (const u32*)(xbg + (rbase + row) * 64 + half * 32);
    u32* dstA = (u32*)&pool[row * 80 + half * 32];
#pragma unroll
    for (int k = 0; k < 16; ++k) {
      u32 u = ga[k];
      float f0 = bf2f((u16)(u & 0xffffu)) * wsc[half * 32 + 2 * k];
      float f1 = bf2f((u16)(u >> 16)) * wsc[half * 32 + 2 * k + 1];
      dstA[k] = (u32)f2bf(f0) | ((u32)f2bf(f1) << 16);
    }
    const u32* gB = (const u32*)(xbg + (sbase + row) * 64 + half * 32);
    u32* dstB = (u32*)&pool[10240 + row * 80 + half * 32];
#pragma unroll
    for (int k = 0; k < 16; ++k) dstB[k] = gB[k];
    int ab = which ? sbase : rbase;
    int bb = which ? rbase : sbase;
    const u32* gE = (const u32*)(eim + (size_t)(ab + row) * 1024 + bb + half * 64);
    u32* dstE = (u32*)&El[row * 132 + half * 64];
#pragma unroll
    for (int k = 0; k < 16; ++k) dstE[k] = gE[k];
  }
  __syncthreads();
  int lane = t & 63, w = t >> 6;
  int q = lane >> 4, r = lane & 15;
  int wr = w >> 1, wc = w & 1;
  f32x4 z4 = {0.f, 0.f, 0.f, 0.f};
  f32x4 acc[4][4];
#pragma unroll
  for (int mi = 0; mi < 4; ++mi)
#pragma unroll
    for (int ni = 0; ni < 4; ++ni) acc[mi][ni] = z4;
#pragma unroll
  for (int ks = 0; ks < 2; ++ks) {
    bf16x8 af[4], bfr[4];
#pragma unroll
    for (int mi = 0; mi < 4; ++mi)
      af[mi] = *(const bf16x8*)&pool[(wr * 64 + mi * 16 + r) * 80 + ks * 32 + q * 8];
#pragma unroll
    for (int ni = 0; ni < 4; ++ni)
      bfr[ni] = *(const bf16x8*)&pool[10240 + (wc * 64 + ni * 16 + r) * 80 + ks * 32 + q * 8];
#pragma unroll
    for (int mi = 0; mi < 4; ++mi)
#pragma unroll
      for (int ni = 0; ni < 4; ++ni) acc[mi][ni] = MFMA16(af[mi], bfr[ni], acc[mi][ni]);
  }
  float w64 = W[64 * 64 + c];
  float bsv = bias[c];
#pragma unroll
  for (int mi = 0; mi < 4; ++mi) {
#pragma unroll
    for (int ni = 0; ni < 4; ++ni) {
      int col = wc * 64 + ni * 16 + r;
#pragma unroll
      for (int tt = 0; tt < 4; ++tt) {
        int row2 = wr * 64 + mi * 16 + q * 4 + tt;
        float e = (float)(which ? El[col * 132 + row2] : El[row2 * 132 + col]);
        acc[mi][ni][tt] = fmaxf(acc[mi][ni][tt] + e * w64 + bsv, 0.f);
      }
    }
  }
  __syncthreads();  // all frag reads of pool done
#pragma unroll
  for (int mi = 0; mi < 4; ++mi)
#pragma unroll
    for (int ni = 0; ni < 4; ++ni) {
      int col = wc * 64 + ni * 16 + r;
#pragma unroll
      for (int tt = 0; tt < 4; ++tt) {
        int row2 = wr * 64 + mi * 16 + q * 4 + tt;
        pool[row2 * 136 + col] = f2bf(acc[mi][ni][tt]);
      }
    }
  __syncthreads();
  {
    int rseg = t >> 4, cseg = t & 15;
#pragma unroll
    for (int it = 0; it < 8; ++it) {
      int row = it * 16 + rseg;
      uint4 v = *(const uint4*)&pool[row * 136 + cseg * 8];
      *(uint4*)(outp + (size_t)(rbase + row) * 1024 + sbase + cseg * 8) = v;
    }
  }
}

// ---------------- batched prod GEMM (16 channels per launch) ----------------
__global__ __launch_bounds__(256, 3) void k_prodgemm(
    const u16* __restrict__ x1tg, const u16* __restrict__ x2tg,
    u16* __restrict__ prod, int cbase) {
  __shared__ u16 pool[17408];
  int b = blockIdx.x;  // grid 1024 = 64 tiles x 16 ch (cl low bits)
  int cl = b & 15;
  int tile = b >> 4;
  int i0 = (tile >> 3) * 128, j0 = (tile & 7) * 128;
  const u16* Ap = x1tg + (size_t)cl * 1048576;
  const u16* Bp = x2tg + (size_t)cl * 1048576;
  u16* Pp = prod + (size_t)(cbase + cl) * 1048576;
  int t = threadIdx.x, lane = t & 63, w = t >> 6;
  int q = lane >> 4, r = lane & 15;
  int wr = w >> 1, wc = w & 1;
  int lrow = lane >> 3, lcol = (lane & 7) * 8;
  f32x4 z4 = {0.f, 0.f, 0.f, 0.f};
  f32x4 acc[4][4];
#pragma unroll
  for (int mi = 0; mi < 4; ++mi)
#pragma unroll
    for (int ni = 0; ni < 4; ++ni) acc[mi][ni] = z4;
  for (int kk = 0; kk < 1024; kk += 64) {
    __syncthreads();
#pragma unroll
    for (int s8 = 0; s8 < 4; ++s8) {
      int rowbase = w * 32 + s8 * 8;
      int grow = rowbase + lrow;
      __builtin_amdgcn_global_load_lds(
          (gas1)(Ap + (size_t)(i0 + grow) * 1024 + kk + lcol),
          (las3)&pool[rowbase * 64], 16, 0, 0);
      __builtin_amdgcn_global_load_lds(
          (gas1)(Bp + (size_t)(j0 + grow) * 1024 + kk + lcol),
          (las3)&pool[8192 + rowbase * 64], 16, 0, 0);
    }
    __syncthreads();
#pragma unroll
    for (int ks = 0; ks < 2; ++ks) {
      bf16x8 af[4], bfr[4];
#pragma unroll
      for (int mi = 0; mi < 4; ++mi)
        af[mi] = *(const bf16x8*)&pool[(wr * 64 + mi * 16 + r) * 64 + ks * 32 + q * 8];
#pragma unroll
      for (int ni = 0; ni < 4; ++ni)
        bfr[ni] = *(const bf16x8*)&pool[8192 + (wc * 64 + ni * 16 + r) * 64 + ks * 32 + q * 8];
#pragma unroll
      for (int mi = 0; mi < 4; ++mi)
#pragma unroll
        for (int ni = 0; ni < 4; ++ni) acc[mi][ni] = MFMA16(af[mi], bfr[ni], acc[mi][ni]);
    }
  }
  __syncthreads();
#pragma unroll
  for (int mi = 0; mi < 4; ++mi)
#pragma unroll
    for (int ni = 0; ni < 4; ++ni) {
      int col = wc * 64 + ni * 16 + r;
#pragma unroll
      for (int tt = 0; tt < 4; ++tt) {
        int row2 = wr * 64 + mi * 16 + q * 4 + tt;
        pool[row2 * 136 + col] = f2bf(acc[mi][ni][tt]);
      }
    }
  __syncthreads();
  {
    int rseg = t >> 4, cseg = t & 15;
#pragma unroll
    for (int it = 0; it < 8; ++it) {
      int row = it * 16 + rseg;
      uint4 v = *(const uint4*)&pool[row * 136 + cseg * 8];
      *(uint4*)(Pp + (size_t)(i0 + row) * 1024 + j0 + cseg * 8) = v;
    }
  }
}

// ---------------- T = [x_i*x_j | eim | prod] @ m3W + b3 (IN PLACE over prod) --
// R7: prod staging = coalesced global (4 lanes/plane, 256B contig) -> scratch
// (stride 130: writes & transpose reads 2-way free) -> A (free writes).
// Also zeroes the S/SS stats buffers (dead-x1tg overlay) in its prologue.
__global__ __launch_bounds__(256, 2) void k_buildT(
    const u16* __restrict__ xbg, const unsigned char* __restrict__ eim,
    u16* PT, const float* __restrict__ m3W, const float* __restrict__ m3b,
    float* __restrict__ S, float* __restrict__ SS) {
  __shared__ u16 A[128 * 136];      // [j][k]; Cs alias rows 0..63
  __shared__ u16 Wt[64 * 136];      // Wt[c][k]
  __shared__ u16 scratch[64 * 130]; // prod bounce: [plane][128j + 2 pad]
  __shared__ float xi[64];
  int i = blockIdx.x;  // grid 1024
  int t = threadIdx.x, lane = t & 63, w = t >> 6;
  int q = lane >> 4, r = lane & 15;
  {
    int zidx = i * 256 + t;
    if (zidx < 65536) { S[zidx] = 0.f; SS[zidx] = 0.f; }
  }
  if (t < 64) xi[t] = bf2f(xbg[i * 64 + t]);
  {
    int row = t >> 1, half = t & 1;
    int rsrc = row < 64 ? row : row + 1;  // skip eim row 64
    const float4* gw = (const float4*)(m3W + rsrc * 64 + half * 32);
#pragma unroll
    for (int k = 0; k < 8; ++k) {
      float4 f = gw[k];
      Wt[(half * 32 + 4 * k + 0) * 136 + row] = f2bf(f.x);
      Wt[(half * 32 + 4 * k + 1) * 136 + row] = f2bf(f.y);
      Wt[(half * 32 + 4 * k + 2) * 136 + row] = f2bf(f.z);
      Wt[(half * 32 + 4 * k + 3) * 136 + row] = f2bf(f.w);
    }
  }
  float w64c[4], b3c[4];
#pragma unroll
  for (int ni = 0; ni < 4; ++ni) {
    int cc = ni * 16 + r;
    w64c[ni] = m3W[64 * 64 + cc];
    b3c[ni] = m3b[cc];
  }
  for (int jc = 0; jc < 8; ++jc) {
    int j0 = jc * 128;
    __syncthreads();  // prior Cs/scratch reads done; (jc=0) orders Wt/xi
    {
      // x-part: A[jj][0..63] = x[j0+jj,:] * x[i,:]
      int jj = t >> 1, half = t & 1;
      const u32* gx = (const u32*)(xbg + (j0 + jj) * 64 + half * 32);
      u32* dst = (u32*)&A[jj * 136 + half * 32];
#pragma unroll
      for (int k = 0; k < 16; ++k) {
        u32 u = gx[k];
        float f0 = bf2f((u16)(u & 0xffffu)) * xi[half * 32 + 2 * k];
        float f1 = bf2f((u16)(u >> 16)) * xi[half * 32 + 2 * k + 1];
        dst[k] = (u32)f2bf(f0) | ((u32)f2bf(f1) << 16);
      }
      // prod-part stage 1: coalesced global -> scratch (4 lanes per plane)
      int p = t >> 2, pt = t & 3;
      const uint4* gp = (const uint4*)(PT + (size_t)p * 1048576 + (size_t)i * 1024 + j0 + pt * 32);
      uint4 v0 = gp[0], v1 = gp[1], v2 = gp[2], v3 = gp[3];
      u32* sw = (u32*)&scratch[p * 130 + pt * 32];  // 260p+64pt bytes, 4B aligned
      sw[0] = v0.x; sw[1] = v0.y; sw[2] = v0.z; sw[3] = v0.w;
      sw[4] = v1.x; sw[5] = v1.y; sw[6] = v1.z; sw[7] = v1.w;
      sw[8] = v2.x; sw[9] = v2.y; sw[10] = v2.z; sw[11] = v2.w;
      sw[12] = v3.x; sw[13] = v3.y; sw[14] = v3.z; sw[15] = v3.w;
    }
    __syncthreads();
    {
      // prod-part stage 2: scratch -> A transpose (reads 2-way, writes free)
#pragma unroll
      for (int jj2 = 0; jj2 < 16; ++jj2) {
        int jr = w * 32 + jj2 * 2;
        u32 two = *(const u32*)&scratch[lane * 130 + jr];
        A[jr * 136 + 64 + lane] = (u16)(two & 0xffffu);
        A[(jr + 1) * 136 + 64 + lane] = (u16)(two >> 16);
      }
    }
    __syncthreads();
    f32x4 z4 = {0.f, 0.f, 0.f, 0.f};
    f32x4 acc[2][4];
#pragma unroll
    for (int mi = 0; mi < 2; ++mi)
#pragma unroll
      for (int ni = 0; ni < 4; ++ni) acc[mi][ni] = z4;
#pragma unroll
    for (int ks = 0; ks < 4; ++ks) {
      bf16x8 af[2], bfr[4];
#pragma unroll
      for (int mi = 0; mi < 2; ++mi)
        af[mi] = *(const bf16x8*)&A[(w * 32 + mi * 16 + r) * 136 + ks * 32 + q * 8];
#pragma unroll
      for (int ni = 0; ni < 4; ++ni)
        bfr[ni] = *(const bf16x8*)&Wt[(ni * 16 + r) * 136 + ks * 32 + q * 8];
#pragma unroll
      for (int mi = 0; mi < 2; ++mi)
#pragma unroll
        for (int ni = 0; ni < 4; ++ni) acc[mi][ni] = MFMA16(af[mi], bfr[ni], acc[mi][ni]);
    }
#pragma unroll
    for (int mi = 0; mi < 2; ++mi) {
#pragma unroll
      for (int tt = 0; tt < 4; ++tt) {
        int jj = w * 32 + mi * 16 + q * 4 + tt;
        float ev = (float)eim[(size_t)i * 1024 + j0 + jj];
#pragma unroll
        for (int ni = 0; ni < 4; ++ni)
          acc[mi][ni][tt] = acc[mi][ni][tt] + ev * w64c[ni] + b3c[ni];
      }
    }
    __syncthreads();  // all frag reads of A done before Cs overwrite
#pragma unroll
    for (int mi = 0; mi < 2; ++mi)
#pragma unroll
      for (int ni = 0; ni < 4; ++ni) {
        int cc = ni * 16 + r;
#pragma unroll
        for (int tt = 0; tt < 4; ++tt) {
          int jj = w * 32 + mi * 16 + q * 4 + tt;
          A[cc * 136 + jj] = f2bf(acc[mi][ni][tt]);
        }
      }
    __syncthreads();
    {
      int cc2 = t >> 2, q64 = t & 3;
#pragma unroll
      for (int k = 0; k < 4; ++k) {
        uint4 v = *(const uint4*)&A[cc2 * 136 + q64 * 32 + k * 8];
        *(uint4*)(PT + (size_t)cc2 * 1048576 + (size_t)i * 1024 + j0 + q64 * 32 + k * 8) = v;
      }
    }
  }
}

// ---------------- graph-norm stats, pass 1: coalesced partial sums ----------
__global__ void k_stats(const u16* __restrict__ Tg, float* __restrict__ S,
                        float* __restrict__ SS) {
  int b = blockIdx.x;  // grid 512 = 64 c x 8 i-chunks
  int c = b >> 3, ic = b & 7;
  int t = threadIdx.x;  // 256; thread covers j = 4t..4t+3
  const u16* base = Tg + (size_t)c * 1048576 + (size_t)ic * 131072 + t * 4;
  float s0 = 0.f, s1 = 0.f, s2 = 0.f, s3 = 0.f;
  float q0 = 0.f, q1 = 0.f, q2 = 0.f, q3 = 0.f;
  for (int ii = 0; ii < 128; ++ii) {
    uint2 u = *(const uint2*)(base + (size_t)ii * 1024);
    float v0 = bf2f((u16)(u.x & 0xffffu)), v1 = bf2f((u16)(u.x >> 16));
    float v2 = bf2f((u16)(u.y & 0xffffu)), v3 = bf2f((u16)(u.y >> 16));
    s0 += v0; q0 += v0 * v0;
    s1 += v1; q1 += v1 * v1;
    s2 += v2; q2 += v2 * v2;
    s3 += v3; q3 += v3 * v3;
  }
  int base2 = c * 1024 + t * 4;
  atomicAdd(&S[base2 + 0], s0);
  atomicAdd(&S[base2 + 1], s1);
  atomicAdd(&S[base2 + 2], s2);
  atomicAdd(&S[base2 + 3], s3);
  atomicAdd(&SS[base2 + 0], q0);
  atomicAdd(&SS[base2 + 1], q1);
  atomicAdd(&SS[base2 + 2], q2);
  atomicAdd(&SS[base2 + 3], q3);
}

// ---------------- graph-norm stats, pass 2: finalize ----------
__global__ void k_statsfin(const float* __restrict__ S, const float* __restrict__ SS,
                           const float* __restrict__ gn3w, const float* __restrict__ gn3b,
                           const float* __restrict__ gn3a,
                           float* __restrict__ normA, float* __restrict__ normB) {
  int idx = blockIdx.x * 256 + threadIdx.x;  // grid 256 -> 65536 = j*64+c
  int c = idx & 63, j = idx >> 6;
  float sum = S[c * 1024 + j];
  float ssum = SS[c * 1024 + j];
  float m = sum * (1.f / 1024.f);
  float a = gn3a[c];
  float var = ssum * (1.f / 1024.f) - (2.f * a - a * a) * m * m;
  float sc = gn3w[c] * rsqrtf(fmaxf(var, 0.f) + 1e-5f);
  normA[idx] = sc;
  normB[idx] = gn3b[c] - sc * a * m;
}

// ---------------- gather + symmetric product + final dot ----------------
__global__ void k_final(const u16* __restrict__ Tg, const float* __restrict__ normA,
                        const float* __restrict__ normB, const int* __restrict__ pos,
                        const float* __restrict__ ldW, const float* __restrict__ ldb,
                        float* __restrict__ out) {
  int t = threadIdx.x, w = t >> 6, lane = t & 63;  // grid 2048 x 256, wave/pos
  int p = blockIdx.x * 4 + w;
  int i = pos[2 * p], j = pos[2 * p + 1];
  float t1 = bf2f(Tg[(size_t)lane * 1048576 + (size_t)i * 1024 + j]);
  float y1 = fmaxf(normA[j * 64 + lane] * t1 + normB[j * 64 + lane], 0.f);
  float t2 = bf2f(Tg[(size_t)lane * 1048576 + (size_t)j * 1024 + i]);
  float y2 = fmaxf(normA[i * 64 + lane] * t2 + normB[i * 64 + lane], 0.f);
  float z = y1 * y2 * ldW[lane];
#pragma unroll
  for (int off = 32; off > 0; off >>= 1) z += __shfl_down(z, off, 64);
  if (lane == 0) out[p] = z + ldb[0];
}

extern "C" void kernel_launch(void* const* d_in, const int* in_sizes, int n_in,
                              void* d_out, int out_size, void* d_ws, size_t ws_size,
                              hipStream_t stream) {
  const int* xids   = (const int*)d_in[0];
  const int* ei     = (const int*)d_in[1];
  const int* pos    = (const int*)d_in[2];
  const float* emb  = (const float*)d_in[3];
  const float* gW0  = (const float*)d_in[4];
  const float* gb0  = (const float*)d_in[5];
  const float* gnw0 = (const float*)d_in[6];
  const float* gnb0 = (const float*)d_in[7];
  const float* gna0 = (const float*)d_in[8];
  const float* gW1  = (const float*)d_in[9];
  const float* gb1  = (const float*)d_in[10];
  const float* gnw1 = (const float*)d_in[11];
  const float* gnb1 = (const float*)d_in[12];
  const float* gna1 = (const float*)d_in[13];
  const float* m1W  = (const float*)d_in[14];
  const float* m1b  = (const float*)d_in[15];
  const float* m2W  = (const float*)d_in[16];
  const float* m2b  = (const float*)d_in[17];
  const float* m3W  = (const float*)d_in[18];
  const float* m3b  = (const float*)d_in[19];
  const float* gn3w = (const float*)d_in[20];
  const float* gn3b = (const float*)d_in[21];
  const float* gn3a = (const float*)d_in[22];
  const float* ldW  = (const float*)d_in[23];
  const float* ldb  = (const float*)d_in[24];

  char* ws = (char*)d_ws;
  float* xf   = (float*)(ws + 0);
  float* h    = (float*)(ws + 262144);
  float* agg  = (float*)(ws + 524288);
  float* deg  = (float*)(ws + 786432);
  u16*   xb   = (u16*)(ws + 790528);
  unsigned char* eim = (unsigned char*)(ws + 921600);
  float* normA = (float*)(ws + 1970176);
  float* normB = (float*)(ws + 2232320);
  u16* x1tg = (u16*)(ws + 2494464);
  u16* x2tg = (u16*)(ws + 36048896);
  u16* prod = (u16*)(ws + 69603328);  // later overwritten in place by T
  // stats partials overlay the dead x1tg region (zeroed by k_buildT prologue)
  float* Sp  = (float*)x1tg;
  float* SSp = Sp + 65536;
  float* out = (float*)d_out;

  k_setup<<<1024, 256, 0, stream>>>(xids, emb, xf, deg, (u32*)eim);
  k_edges<<<64, 256, 0, stream>>>(ei, deg, eim);
  // GCN layer 0
  k_gemm_node<<<1024, 64, 0, stream>>>(xf, gW0, gb0, deg, h, agg);
  k_agg<<<4096, 256, 0, stream>>>(ei, deg, h, agg);
  k_gnorm<<<64, 256, 0, stream>>>(agg, gnw0, gnb0, gna0, xf, xb, 0);
  // GCN layer 1
  k_gemm_node<<<1024, 64, 0, stream>>>(xf, gW1, gb1, deg, h, agg);
  k_agg<<<4096, 256, 0, stream>>>(ei, deg, h, agg);
  k_gnorm<<<64, 256, 0, stream>>>(agg, gnw1, gnb1, gna1, xf, xb, 1);
  // pairwise maps + batched 1024^3 GEMM, 4 channel-groups of 16
  for (int g = 0; g < 4; ++g) {
    k_build12<<<2048, 256, 0, stream>>>(xb, eim, m1W, m1b, m2W, m2b, x1tg, x2tg, g * 16);
    k_prodgemm<<<1024, 256, 0, stream>>>(x1tg, x2tg, prod, g * 16);
  }
  // T tensor (in place over prod) + stats + final
  k_buildT<<<1024, 256, 0, stream>>>(xb, eim, prod, m3W, m3b, Sp, SSp);
  k_stats<<<512, 256, 0, stream>>>(prod, Sp, SSp);
  k_statsfin<<<256, 256, 0, stream>>>(Sp, SSp, gn3w, gn3b, gn3a, normA, normB);
  k_final<<<2048, 256, 0, stream>>>(prod, normA, normB, pos, ldW, ldb, out);
}

// Round 8
// 530.224 us; speedup vs baseline: 1.1961x; 1.1084x over previous
//
#include <hip/hip_runtime.h>

// FWLNet pipeline; see R5-R7 notes.
//
// R8 (from R7 pass @587.7us):
//  - k_buildT: 64-j chunks (LDS 69->43.5KB -> 3 blocks/CU); full-line T
//    stores (8 lanes x uint4 = contiguous 128B per plane row; R7 pattern
//    1/4-covered lines -> WRITE_SIZE 195MB, ~1.45x amplification).
//  - k_prodgemm: launch_bounds(256,4) (LDS 34KB fits 4; grid = exactly
//    4 blocks/CU -> zero tail).
//
// ws layout unchanged (~194.4 MB).

typedef unsigned short u16;
typedef unsigned int u32;

#define DI static __device__ __forceinline__

DI float bf2f(u16 u) { union { u32 i; float f; } v; v.i = ((u32)u) << 16; return v.f; }
DI u16 f2bf(float f) {
  union { float f; u32 i; } v; v.f = f;
  u32 u = v.i;
  return (u16)((u + 0x7fffu + ((u >> 16) & 1u)) >> 16);
}

typedef __bf16 bf16x8 __attribute__((ext_vector_type(8)));
typedef float f32x4 __attribute__((ext_vector_type(4)));

#define MFMA16(a, b, c) __builtin_amdgcn_mfma_f32_16x16x32_bf16((a), (b), (c), 0, 0, 0)

typedef const __attribute__((address_space(1))) u32* gas1;
typedef __attribute__((address_space(3))) u32* las3;

// ---------------- node pipeline ----------------

__global__ void k_setup(const int* __restrict__ xids, const float* __restrict__ emb,
                        float* __restrict__ xf, float* __restrict__ deg,
                        u32* __restrict__ eimu) {
  int g = blockIdx.x * 256 + threadIdx.x;  // grid 1024
  if (g < 262144) eimu[g] = 0u;
  if (g < 1024) deg[g] = 1.0f;  // self-loop
  if (g < 65536) {
    int i = g >> 6, d = g & 63;
    xf[g] = emb[xids[i] * 64 + d];
  }
}

__global__ void k_edges(const int* __restrict__ ei, float* __restrict__ deg,
                        unsigned char* __restrict__ eim) {
  int e = blockIdx.x * 256 + threadIdx.x;  // grid 64
  if (e < 16384) {
    int s = ei[e], d = ei[16384 + e];
    atomicAdd(&deg[d], 1.0f);
    eim[s * 1024 + d] = 1;
  }
}

__global__ void k_gemm_node(const float* __restrict__ xf, const float* __restrict__ W,
                            const float* __restrict__ gb, const float* __restrict__ deg,
                            float* __restrict__ h, float* __restrict__ agg) {
  __shared__ float xrow[64];
  int i = blockIdx.x, c = threadIdx.x;  // grid 1024 x 64
  xrow[c] = xf[i * 64 + c];
  __syncthreads();
  float s = 0.f;
#pragma unroll
  for (int d = 0; d < 64; ++d) s += xrow[d] * W[d * 64 + c];
  h[i * 64 + c] = s;
  agg[i * 64 + c] = s / deg[i] + gb[c];
}

__global__ void k_agg(const int* __restrict__ ei, const float* __restrict__ deg,
                      const float* __restrict__ h, float* __restrict__ agg) {
  int g = blockIdx.x * 256 + threadIdx.x;  // grid 4096 -> e x c
  int e = g >> 6, c = g & 63;
  int s = ei[e], d = ei[16384 + e];
  float nrm = rsqrtf(deg[s]) * rsqrtf(deg[d]);
  atomicAdd(&agg[d * 64 + c], nrm * h[s * 64 + c]);
}

__global__ void k_gnorm(const float* __restrict__ agg, const float* __restrict__ gw,
                        const float* __restrict__ gbb, const float* __restrict__ ga,
                        float* __restrict__ xf, u16* __restrict__ xb, int last) {
  int c = blockIdx.x, t = threadIdx.x;  // grid 64 x 256
  float s = 0.f, ss = 0.f;
  for (int i = t; i < 1024; i += 256) {
    float v = agg[i * 64 + c];
    s += v; ss += v * v;
  }
  __shared__ float Ls[256], Lss[256];
  Ls[t] = s; Lss[t] = ss;
  __syncthreads();
  for (int off = 128; off > 0; off >>= 1) {
    if (t < off) { Ls[t] += Ls[t + off]; Lss[t] += Lss[t + off]; }
    __syncthreads();
  }
  float m = Ls[0] * (1.f / 1024.f);
  float a = ga[c];
  float var = Lss[0] * (1.f / 1024.f) - (2.f * a - a * a) * m * m;
  float sc = gw[c] * rsqrtf(fmaxf(var, 0.f) + 1e-5f);
  float bb = gbb[c];
  for (int i = t; i < 1024; i += 256) {
    float v = agg[i * 64 + c];
    float y = fmaxf(sc * (v - a * m) + bb, 0.f);
    xf[i * 64 + c] = y;
    if (last) xb[i * 64 + c] = f2bf(y);
  }
}

// ---------------- x1t / x2T builder (16 channels per launch) ----------------
__global__ __launch_bounds__(256, 2) void k_build12(
    const u16* __restrict__ xbg, const unsigned char* __restrict__ eim,
    const float* __restrict__ m1W, const float* __restrict__ m1b,
    const float* __restrict__ m2W, const float* __restrict__ m2b,
    u16* __restrict__ x1tg, u16* __restrict__ x2tg, int cbase) {
  // pool: As[128][80] (0..10239) | Bs[128][80] (10240..20479); Cs aliases 0..17407
  __shared__ u16 pool[20480];
  __shared__ unsigned char El[128 * 132];
  __shared__ float wsc[64];
  int b = blockIdx.x;  // grid 2048 = 2(which) x 64 tiles x 16 ch
  int cl = b & 15;
  int c = cbase + cl;
  int rest = b >> 4;
  int which = rest >> 6;
  int t6 = rest & 63;
  int rbase = (t6 >> 3) * 128, sbase = (t6 & 7) * 128;
  const float* W = which ? m2W : m1W;
  const float* bias = which ? m2b : m1b;
  u16* outp = (which ? x2tg : x1tg) + (size_t)cl * 1048576;
  int t = threadIdx.x;
  if (t < 64) wsc[t] = W[t * 64 + c];
  __syncthreads();
  {
    int row = t >> 1, half = t & 1;
    const u32* ga = (const u32*)(xbg + (rbase + row) * 64 + half * 32);
    u32* dstA = (u32*)&pool[row * 80 + half * 32];
#pragma unroll
    for (int k = 0; k < 16; ++k) {
      u32 u = ga[k];
      float f0 = bf2f((u16)(u & 0xffffu)) * wsc[half * 32 + 2 * k];
      float f1 = bf2f((u16)(u >> 16)) * wsc[half * 32 + 2 * k + 1];
      dstA[k] = (u32)f2bf(f0) | ((u32)f2bf(f1) << 16);
    }
    const u32* gB = (const u32*)(xbg + (sbase + row) * 64 + half * 32);
    u32* dstB = (u32*)&pool[10240 + row * 80 + half * 32];
#pragma unroll
    for (int k = 0; k < 16; ++k) dstB[k] = gB[k];
    int ab = which ? sbase : rbase;
    int bb = which ? rbase : sbase;
    const u32* gE = (const u32*)(eim + (size_t)(ab + row) * 1024 + bb + half * 64);
    u32* dstE = (u32*)&El[row * 132 + half * 64];
#pragma unroll
    for (int k = 0; k < 16; ++k) dstE[k] = gE[k];
  }
  __syncthreads();
  int lane = t & 63, w = t >> 6;
  int q = lane >> 4, r = lane & 15;
  int wr = w >> 1, wc = w & 1;
  f32x4 z4 = {0.f, 0.f, 0.f, 0.f};
  f32x4 acc[4][4];
#pragma unroll
  for (int mi = 0; mi < 4; ++mi)
#pragma unroll
    for (int ni = 0; ni < 4; ++ni) acc[mi][ni] = z4;
#pragma unroll
  for (int ks = 0; ks < 2; ++ks) {
    bf16x8 af[4], bfr[4];
#pragma unroll
    for (int mi = 0; mi < 4; ++mi)
      af[mi] = *(const bf16x8*)&pool[(wr * 64 + mi * 16 + r) * 80 + ks * 32 + q * 8];
#pragma unroll
    for (int ni = 0; ni < 4; ++ni)
      bfr[ni] = *(const bf16x8*)&pool[10240 + (wc * 64 + ni * 16 + r) * 80 + ks * 32 + q * 8];
#pragma unroll
    for (int mi = 0; mi < 4; ++mi)
#pragma unroll
      for (int ni = 0; ni < 4; ++ni) acc[mi][ni] = MFMA16(af[mi], bfr[ni], acc[mi][ni]);
  }
  float w64 = W[64 * 64 + c];
  float bsv = bias[c];
#pragma unroll
  for (int mi = 0; mi < 4; ++mi) {
#pragma unroll
    for (int ni = 0; ni < 4; ++ni) {
      int col = wc * 64 + ni * 16 + r;
#pragma unroll
      for (int tt = 0; tt < 4; ++tt) {
        int row2 = wr * 64 + mi * 16 + q * 4 + tt;
        float e = (float)(which ? El[col * 132 + row2] : El[row2 * 132 + col]);
        acc[mi][ni][tt] = fmaxf(acc[mi][ni][tt] + e * w64 + bsv, 0.f);
      }
    }
  }
  __syncthreads();
#pragma unroll
  for (int mi = 0; mi < 4; ++mi)
#pragma unroll
    for (int ni = 0; ni < 4; ++ni) {
      int col = wc * 64 + ni * 16 + r;
#pragma unroll
      for (int tt = 0; tt < 4; ++tt) {
        int row2 = wr * 64 + mi * 16 + q * 4 + tt;
        pool[row2 * 136 + col] = f2bf(acc[mi][ni][tt]);
      }
    }
  __syncthreads();
  {
    int rseg = t >> 4, cseg = t & 15;
#pragma unroll
    for (int it = 0; it < 8; ++it) {
      int row = it * 16 + rseg;
      uint4 v = *(const uint4*)&pool[row * 136 + cseg * 8];
      *(uint4*)(outp + (size_t)(rbase + row) * 1024 + sbase + cseg * 8) = v;
    }
  }
}

// ---------------- batched prod GEMM (16 channels per launch) ----------------
__global__ __launch_bounds__(256, 4) void k_prodgemm(
    const u16* __restrict__ x1tg, const u16* __restrict__ x2tg,
    u16* __restrict__ prod, int cbase) {
  __shared__ u16 pool[17408];
  int b = blockIdx.x;  // grid 1024 = 64 tiles x 16 ch (cl low bits)
  int cl = b & 15;
  int tile = b >> 4;
  int i0 = (tile >> 3) * 128, j0 = (tile & 7) * 128;
  const u16* Ap = x1tg + (size_t)cl * 1048576;
  const u16* Bp = x2tg + (size_t)cl * 1048576;
  u16* Pp = prod + (size_t)(cbase + cl) * 1048576;
  int t = threadIdx.x, lane = t & 63, w = t >> 6;
  int q = lane >> 4, r = lane & 15;
  int wr = w >> 1, wc = w & 1;
  int lrow = lane >> 3, lcol = (lane & 7) * 8;
  f32x4 z4 = {0.f, 0.f, 0.f, 0.f};
  f32x4 acc[4][4];
#pragma unroll
  for (int mi = 0; mi < 4; ++mi)
#pragma unroll
    for (int ni = 0; ni < 4; ++ni) acc[mi][ni] = z4;
  for (int kk = 0; kk < 1024; kk += 64) {
    __syncthreads();
#pragma unroll
    for (int s8 = 0; s8 < 4; ++s8) {
      int rowbase = w * 32 + s8 * 8;
      int grow = rowbase + lrow;
      __builtin_amdgcn_global_load_lds(
          (gas1)(Ap + (size_t)(i0 + grow) * 1024 + kk + lcol),
          (las3)&pool[rowbase * 64], 16, 0, 0);
      __builtin_amdgcn_global_load_lds(
          (gas1)(Bp + (size_t)(j0 + grow) * 1024 + kk + lcol),
          (las3)&pool[8192 + rowbase * 64], 16, 0, 0);
    }
    __syncthreads();
#pragma unroll
    for (int ks = 0; ks < 2; ++ks) {
      bf16x8 af[4], bfr[4];
#pragma unroll
      for (int mi = 0; mi < 4; ++mi)
        af[mi] = *(const bf16x8*)&pool[(wr * 64 + mi * 16 + r) * 64 + ks * 32 + q * 8];
#pragma unroll
      for (int ni = 0; ni < 4; ++ni)
        bfr[ni] = *(const bf16x8*)&pool[8192 + (wc * 64 + ni * 16 + r) * 64 + ks * 32 + q * 8];
#pragma unroll
      for (int mi = 0; mi < 4; ++mi)
#pragma unroll
        for (int ni = 0; ni < 4; ++ni) acc[mi][ni] = MFMA16(af[mi], bfr[ni], acc[mi][ni]);
    }
  }
  __syncthreads();
#pragma unroll
  for (int mi = 0; mi < 4; ++mi)
#pragma unroll
    for (int ni = 0; ni < 4; ++ni) {
      int col = wc * 64 + ni * 16 + r;
#pragma unroll
      for (int tt = 0; tt < 4; ++tt) {
        int row2 = wr * 64 + mi * 16 + q * 4 + tt;
        pool[row2 * 136 + col] = f2bf(acc[mi][ni][tt]);
      }
    }
  __syncthreads();
  {
    int rseg = t >> 4, cseg = t & 15;
#pragma unroll
    for (int it = 0; it < 8; ++it) {
      int row = it * 16 + rseg;
      uint4 v = *(const uint4*)&pool[row * 136 + cseg * 8];
      *(uint4*)(Pp + (size_t)(i0 + row) * 1024 + j0 + cseg * 8) = v;
    }
  }
}

// ---------------- T = [x_i*x_j | eim | prod] @ m3W + b3 (IN PLACE over prod) --
// R8: 64-j chunks -> LDS ~43.5KB (3 blocks/CU); full-line T stores.
__global__ __launch_bounds__(256, 3) void k_buildT(
    const u16* __restrict__ xbg, const unsigned char* __restrict__ eim,
    u16* PT, const float* __restrict__ m3W, const float* __restrict__ m3b,
    float* __restrict__ S, float* __restrict__ SS) {
  __shared__ u16 A[64 * 136];      // [j][k]: k<64 x-part, k>=64 prod-part; Cs alias
  __shared__ u16 Wt[64 * 136];     // Wt[c][k]
  __shared__ u16 scratch[64 * 66]; // prod bounce: [plane][64j + 2 pad]
  __shared__ float xi[64];
  int i = blockIdx.x;  // grid 1024
  int t = threadIdx.x, lane = t & 63, w = t >> 6;
  int q = lane >> 4, r = lane & 15;
  {
    int zidx = i * 256 + t;
    if (zidx < 65536) { S[zidx] = 0.f; SS[zidx] = 0.f; }
  }
  if (t < 64) xi[t] = bf2f(xbg[i * 64 + t]);
  {
    int row = t >> 1, half = t & 1;
    int rsrc = row < 64 ? row : row + 1;  // skip eim row 64
    const float4* gw = (const float4*)(m3W + rsrc * 64 + half * 32);
#pragma unroll
    for (int k = 0; k < 8; ++k) {
      float4 f = gw[k];
      Wt[(half * 32 + 4 * k + 0) * 136 + row] = f2bf(f.x);
      Wt[(half * 32 + 4 * k + 1) * 136 + row] = f2bf(f.y);
      Wt[(half * 32 + 4 * k + 2) * 136 + row] = f2bf(f.z);
      Wt[(half * 32 + 4 * k + 3) * 136 + row] = f2bf(f.w);
    }
  }
  float w64c[4], b3c[4];
#pragma unroll
  for (int ni = 0; ni < 4; ++ni) {
    int cc = ni * 16 + r;
    w64c[ni] = m3W[64 * 64 + cc];
    b3c[ni] = m3b[cc];
  }
  for (int jc = 0; jc < 16; ++jc) {
    int j0 = jc * 64;
    __syncthreads();  // prior Cs/scratch reads done; (jc=0) orders Wt/xi
    {
      // x-part: A[jj][0..63] = x[j0+jj,:] * x[i,:]  (4 threads/row, 16 cols)
      int jj = t >> 2, quar = t & 3;
      const u32* gx = (const u32*)(xbg + (j0 + jj) * 64 + quar * 16);
      u32* dst = (u32*)&A[jj * 136 + quar * 16];
#pragma unroll
      for (int k = 0; k < 8; ++k) {
        u32 u = gx[k];
        float f0 = bf2f((u16)(u & 0xffffu)) * xi[quar * 16 + 2 * k];
        float f1 = bf2f((u16)(u >> 16)) * xi[quar * 16 + 2 * k + 1];
        dst[k] = (u32)f2bf(f0) | ((u32)f2bf(f1) << 16);
      }
      // prod stage 1: coalesced global -> scratch (4 lanes/plane, 32B each)
      int p = t >> 2, pt = t & 3;
      const uint4* gp = (const uint4*)(PT + (size_t)p * 1048576 + (size_t)i * 1024 + j0 + pt * 16);
      uint4 v0 = gp[0];
      uint2 v1 = ((const uint2*)gp)[2];
      u32* sw = (u32*)&scratch[p * 66 + pt * 16];
      sw[0] = v0.x; sw[1] = v0.y; sw[2] = v0.z; sw[3] = v0.w;
      sw[4] = v1.x; sw[5] = v1.y;
      // 16 elements = 32B? NO: 16 u16 = 32B = 8 u32. Fix: full 32B needs v0+v1(16B+16B)
      uint2 v2 = ((const uint2*)gp)[3];
      sw[6] = v2.x; sw[7] = v2.y;
    }
    __syncthreads();
    {
      // prod stage 2: scratch -> A transpose (row stride 66 -> 2-way free)
#pragma unroll
      for (int jj2 = 0; jj2 < 8; ++jj2) {
        int jr = w * 16 + jj2 * 2;
        u32 two = *(const u32*)&scratch[lane * 66 + jr];
        A[jr * 136 + 64 + lane] = (u16)(two & 0xffffu);
        A[(jr + 1) * 136 + 64 + lane] = (u16)(two >> 16);
      }
    }
    __syncthreads();
    f32x4 z4 = {0.f, 0.f, 0.f, 0.f};
    f32x4 acc[4];
#pragma unroll
    for (int ni = 0; ni < 4; ++ni) acc[ni] = z4;
#pragma unroll
    for (int ks = 0; ks < 4; ++ks) {
      bf16x8 af, bfr[4];
      af = *(const bf16x8*)&A[(w * 16 + r) * 136 + ks * 32 + q * 8];
#pragma unroll
      for (int ni = 0; ni < 4; ++ni)
        bfr[ni] = *(const bf16x8*)&Wt[(ni * 16 + r) * 136 + ks * 32 + q * 8];
#pragma unroll
      for (int ni = 0; ni < 4; ++ni) acc[ni] = MFMA16(af, bfr[ni], acc[ni]);
    }
#pragma unroll
    for (int tt = 0; tt < 4; ++tt) {
      int jj = w * 16 + q * 4 + tt;
      float ev = (float)eim[(size_t)i * 1024 + j0 + jj];
#pragma unroll
      for (int ni = 0; ni < 4; ++ni)
        acc[ni][tt] = acc[ni][tt] + ev * w64c[ni] + b3c[ni];
    }
    __syncthreads();  // all frag reads of A done before Cs overwrite
#pragma unroll
    for (int ni = 0; ni < 4; ++ni) {
      int cc = ni * 16 + r;
#pragma unroll
      for (int tt = 0; tt < 4; ++tt) {
        int jj = w * 16 + q * 4 + tt;
        A[cc * 136 + jj] = f2bf(acc[ni][tt]);
      }
    }
    __syncthreads();
    {
      // full-line stores: 8 lanes x uint4 = 128B contiguous per plane
      int pl = t >> 3, off = (t & 7) * 8;
#pragma unroll
      for (int k = 0; k < 2; ++k) {
        int plane = k * 32 + pl;
        uint4 v = *(const uint4*)&A[plane * 136 + off];
        *(uint4*)(PT + (size_t)plane * 1048576 + (size_t)i * 1024 + j0 + off) = v;
      }
    }
  }
}

// ---------------- graph-norm stats, pass 1: coalesced partial sums ----------
__global__ void k_stats(const u16* __restrict__ Tg, float* __restrict__ S,
                        float* __restrict__ SS) {
  int b = blockIdx.x;  // grid 512 = 64 c x 8 i-chunks
  int c = b >> 3, ic = b & 7;
  int t = threadIdx.x;  // 256; thread covers j = 4t..4t+3
  const u16* base = Tg + (size_t)c * 1048576 + (size_t)ic * 131072 + t * 4;
  float s0 = 0.f, s1 = 0.f, s2 = 0.f, s3 = 0.f;
  float q0 = 0.f, q1 = 0.f, q2 = 0.f, q3 = 0.f;
  for (int ii = 0; ii < 128; ++ii) {
    uint2 u = *(const uint2*)(base + (size_t)ii * 1024);
    float v0 = bf2f((u16)(u.x & 0xffffu)), v1 = bf2f((u16)(u.x >> 16));
    float v2 = bf2f((u16)(u.y & 0xffffu)), v3 = bf2f((u16)(u.y >> 16));
    s0 += v0; q0 += v0 * v0;
    s1 += v1; q1 += v1 * v1;
    s2 += v2; q2 += v2 * v2;
    s3 += v3; q3 += v3 * v3;
  }
  int base2 = c * 1024 + t * 4;
  atomicAdd(&S[base2 + 0], s0);
  atomicAdd(&S[base2 + 1], s1);
  atomicAdd(&S[base2 + 2], s2);
  atomicAdd(&S[base2 + 3], s3);
  atomicAdd(&SS[base2 + 0], q0);
  atomicAdd(&SS[base2 + 1], q1);
  atomicAdd(&SS[base2 + 2], q2);
  atomicAdd(&SS[base2 + 3], q3);
}

// ---------------- graph-norm stats, pass 2: finalize ----------
__global__ void k_statsfin(const float* __restrict__ S, const float* __restrict__ SS,
                           const float* __restrict__ gn3w, const float* __restrict__ gn3b,
                           const float* __restrict__ gn3a,
                           float* __restrict__ normA, float* __restrict__ normB) {
  int idx = blockIdx.x * 256 + threadIdx.x;  // grid 256 -> 65536 = j*64+c
  int c = idx & 63, j = idx >> 6;
  float sum = S[c * 1024 + j];
  float ssum = SS[c * 1024 + j];
  float m = sum * (1.f / 1024.f);
  float a = gn3a[c];
  float var = ssum * (1.f / 1024.f) - (2.f * a - a * a) * m * m;
  float sc = gn3w[c] * rsqrtf(fmaxf(var, 0.f) + 1e-5f);
  normA[idx] = sc;
  normB[idx] = gn3b[c] - sc * a * m;
}

// ---------------- gather + symmetric product + final dot ----------------
__global__ void k_final(const u16* __restrict__ Tg, const float* __restrict__ normA,
                        const float* __restrict__ normB, const int* __restrict__ pos,
                        const float* __restrict__ ldW, const float* __restrict__ ldb,
                        float* __restrict__ out) {
  int t = threadIdx.x, w = t >> 6, lane = t & 63;  // grid 2048 x 256, wave/pos
  int p = blockIdx.x * 4 + w;
  int i = pos[2 * p], j = pos[2 * p + 1];
  float t1 = bf2f(Tg[(size_t)lane * 1048576 + (size_t)i * 1024 + j]);
  float y1 = fmaxf(normA[j * 64 + lane] * t1 + normB[j * 64 + lane], 0.f);
  float t2 = bf2f(Tg[(size_t)lane * 1048576 + (size_t)j * 1024 + i]);
  float y2 = fmaxf(normA[i * 64 + lane] * t2 + normB[i * 64 + lane], 0.f);
  float z = y1 * y2 * ldW[lane];
#pragma unroll
  for (int off = 32; off > 0; off >>= 1) z += __shfl_down(z, off, 64);
  if (lane == 0) out[p] = z + ldb[0];
}

extern "C" void kernel_launch(void* const* d_in, const int* in_sizes, int n_in,
                              void* d_out, int out_size, void* d_ws, size_t ws_size,
                              hipStream_t stream) {
  const int* xids   = (const int*)d_in[0];
  const int* ei     = (const int*)d_in[1];
  const int* pos    = (const int*)d_in[2];
  const float* emb  = (const float*)d_in[3];
  const float* gW0  = (const float*)d_in[4];
  const float* gb0  = (const float*)d_in[5];
  const float* gnw0 = (const float*)d_in[6];
  const float* gnb0 = (const float*)d_in[7];
  const float* gna0 = (const float*)d_in[8];
  const float* gW1  = (const float*)d_in[9];
  const float* gb1  = (const float*)d_in[10];
  const float* gnw1 = (const float*)d_in[11];
  const float* gnb1 = (const float*)d_in[12];
  const float* gna1 = (const float*)d_in[13];
  const float* m1W  = (const float*)d_in[14];
  const float* m1b  = (const float*)d_in[15];
  const float* m2W  = (const float*)d_in[16];
  const float* m2b  = (const float*)d_in[17];
  const float* m3W  = (const float*)d_in[18];
  const float* m3b  = (const float*)d_in[19];
  const float* gn3w = (const float*)d_in[20];
  const float* gn3b = (const float*)d_in[21];
  const float* gn3a = (const float*)d_in[22];
  const float* ldW  = (const float*)d_in[23];
  const float* ldb  = (const float*)d_in[24];

  char* ws = (char*)d_ws;
  float* xf   = (float*)(ws + 0);
  float* h    = (float*)(ws + 262144);
  float* agg  = (float*)(ws + 524288);
  float* deg  = (float*)(ws + 786432);
  u16*   xb   = (u16*)(ws + 790528);
  unsigned char* eim = (unsigned char*)(ws + 921600);
  float* normA = (float*)(ws + 1970176);
  float* normB = (float*)(ws + 2232320);
  u16* x1tg = (u16*)(ws + 2494464);
  u16* x2tg = (u16*)(ws + 36048896);
  u16* prod = (u16*)(ws + 69603328);  // later overwritten in place by T
  float* Sp  = (float*)x1tg;          // stats partials overlay dead x1tg
  float* SSp = Sp + 65536;
  float* out = (float*)d_out;

  k_setup<<<1024, 256, 0, stream>>>(xids, emb, xf, deg, (u32*)eim);
  k_edges<<<64, 256, 0, stream>>>(ei, deg, eim);
  // GCN layer 0
  k_gemm_node<<<1024, 64, 0, stream>>>(xf, gW0, gb0, deg, h, agg);
  k_agg<<<4096, 256, 0, stream>>>(ei, deg, h, agg);
  k_gnorm<<<64, 256, 0, stream>>>(agg, gnw0, gnb0, gna0, xf, xb, 0);
  // GCN layer 1
  k_gemm_node<<<1024, 64, 0, stream>>>(xf, gW1, gb1, deg, h, agg);
  k_agg<<<4096, 256, 0, stream>>>(ei, deg, h, agg);
  k_gnorm<<<64, 256, 0, stream>>>(agg, gnw1, gnb1, gna1, xf, xb, 1);
  // pairwise maps + batched 1024^3 GEMM, 4 channel-groups of 16
  for (int g = 0; g < 4; ++g) {
    k_build12<<<2048, 256, 0, stream>>>(xb, eim, m1W, m1b, m2W, m2b, x1tg, x2tg, g * 16);
    k_prodgemm<<<1024, 256, 0, stream>>>(x1tg, x2tg, prod, g * 16);
  }
  // T tensor (in place over prod) + stats + final
  k_buildT<<<1024, 256, 0, stream>>>(xb, eim, prod, m3W, m3b, Sp, SSp);
  k_stats<<<512, 256, 0, stream>>>(prod, Sp, SSp);
  k_statsfin<<<256, 256, 0, stream>>>(Sp, SSp, gn3w, gn3b, gn3a, normA, normB);
  k_final<<<2048, 256, 0, stream>>>(prod, normA, normB, pos, ldW, ldb, out);
}

// Round 9
// 520.647 us; speedup vs baseline: 1.2181x; 1.0184x over previous
//
#include <hip/hip_runtime.h>

// FWLNet pipeline; see R5-R8 notes.
//
// R9 (from R8 pass @530.2us):
//  - k_build12: one block = 4 channels per (which,tile). Bs/El staged ONCE
//    (was 16x redundant across channel-blocks); As re-staged per channel;
//    dedicated Cs (stride 140 -> ~2-way banks) in two 64-row passes keeps
//    full-line stores. Grid 2048 -> 512 per launch. LDS ~76KB, 2 blocks/CU.
//  - everything else frozen at R8.
//
// ws layout unchanged (~194.4 MB).

typedef unsigned short u16;
typedef unsigned int u32;

#define DI static __device__ __forceinline__

DI float bf2f(u16 u) { union { u32 i; float f; } v; v.i = ((u32)u) << 16; return v.f; }
DI u16 f2bf(float f) {
  union { float f; u32 i; } v; v.f = f;
  u32 u = v.i;
  return (u16)((u + 0x7fffu + ((u >> 16) & 1u)) >> 16);
}

typedef __bf16 bf16x8 __attribute__((ext_vector_type(8)));
typedef float f32x4 __attribute__((ext_vector_type(4)));

#define MFMA16(a, b, c) __builtin_amdgcn_mfma_f32_16x16x32_bf16((a), (b), (c), 0, 0, 0)

typedef const __attribute__((address_space(1))) u32* gas1;
typedef __attribute__((address_space(3))) u32* las3;

// ---------------- node pipeline ----------------

__global__ void k_setup(const int* __restrict__ xids, const float* __restrict__ emb,
                        float* __restrict__ xf, float* __restrict__ deg,
                        u32* __restrict__ eimu) {
  int g = blockIdx.x * 256 + threadIdx.x;  // grid 1024
  if (g < 262144) eimu[g] = 0u;
  if (g < 1024) deg[g] = 1.0f;  // self-loop
  if (g < 65536) {
    int i = g >> 6, d = g & 63;
    xf[g] = emb[xids[i] * 64 + d];
  }
}

__global__ void k_edges(const int* __restrict__ ei, float* __restrict__ deg,
                        unsigned char* __restrict__ eim) {
  int e = blockIdx.x * 256 + threadIdx.x;  // grid 64
  if (e < 16384) {
    int s = ei[e], d = ei[16384 + e];
    atomicAdd(&deg[d], 1.0f);
    eim[s * 1024 + d] = 1;
  }
}

__global__ void k_gemm_node(const float* __restrict__ xf, const float* __restrict__ W,
                            const float* __restrict__ gb, const float* __restrict__ deg,
                            float* __restrict__ h, float* __restrict__ agg) {
  __shared__ float xrow[64];
  int i = blockIdx.x, c = threadIdx.x;  // grid 1024 x 64
  xrow[c] = xf[i * 64 + c];
  __syncthreads();
  float s = 0.f;
#pragma unroll
  for (int d = 0; d < 64; ++d) s += xrow[d] * W[d * 64 + c];
  h[i * 64 + c] = s;
  agg[i * 64 + c] = s / deg[i] + gb[c];
}

__global__ void k_agg(const int* __restrict__ ei, const float* __restrict__ deg,
                      const float* __restrict__ h, float* __restrict__ agg) {
  int g = blockIdx.x * 256 + threadIdx.x;  // grid 4096 -> e x c
  int e = g >> 6, c = g & 63;
  int s = ei[e], d = ei[16384 + e];
  float nrm = rsqrtf(deg[s]) * rsqrtf(deg[d]);
  atomicAdd(&agg[d * 64 + c], nrm * h[s * 64 + c]);
}

__global__ void k_gnorm(const float* __restrict__ agg, const float* __restrict__ gw,
                        const float* __restrict__ gbb, const float* __restrict__ ga,
                        float* __restrict__ xf, u16* __restrict__ xb, int last) {
  int c = blockIdx.x, t = threadIdx.x;  // grid 64 x 256
  float s = 0.f, ss = 0.f;
  for (int i = t; i < 1024; i += 256) {
    float v = agg[i * 64 + c];
    s += v; ss += v * v;
  }
  __shared__ float Ls[256], Lss[256];
  Ls[t] = s; Lss[t] = ss;
  __syncthreads();
  for (int off = 128; off > 0; off >>= 1) {
    if (t < off) { Ls[t] += Ls[t + off]; Lss[t] += Lss[t + off]; }
    __syncthreads();
  }
  float m = Ls[0] * (1.f / 1024.f);
  float a = ga[c];
  float var = Lss[0] * (1.f / 1024.f) - (2.f * a - a * a) * m * m;
  float sc = gw[c] * rsqrtf(fmaxf(var, 0.f) + 1e-5f);
  float bb = gbb[c];
  for (int i = t; i < 1024; i += 256) {
    float v = agg[i * 64 + c];
    float y = fmaxf(sc * (v - a * m) + bb, 0.f);
    xf[i * 64 + c] = y;
    if (last) xb[i * 64 + c] = f2bf(y);
  }
}

// ---------------- x1t / x2T builder: 4 channels per block ----------------
// which=0: x1tg[cl][i][k] = relu( sum_d x[i,d]*m1W[d,c]*x[k,d] + eim[i,k]*w64 + b )
// which=1: x2tg[cl][j][k] = relu( sum_d x[j,d]*m2W[d,c]*x[k,d] + eim[k,j]*w64 + b )
__global__ __launch_bounds__(256, 2) void k_build12(
    const u16* __restrict__ xbg, const unsigned char* __restrict__ eim,
    const float* __restrict__ m1W, const float* __restrict__ m1b,
    const float* __restrict__ m2W, const float* __restrict__ m2b,
    u16* __restrict__ x1tg, u16* __restrict__ x2tg, int cbase) {
  __shared__ u16 As[128 * 80];   // per-channel scaled A tile
  __shared__ u16 Bs[128 * 80];   // shared raw B tile (staged once)
  __shared__ u16 Cs[64 * 140];   // store transpose buffer (stride 140: ~2-way)
  __shared__ unsigned char El[128 * 132];  // shared eim tile (staged once)
  __shared__ float wsc[64];
  int b = blockIdx.x;  // grid 512 = 2(which) x 64 tiles x 4 channel-quads
  int cg = b & 3;
  int rest = b >> 2;
  int which = rest >> 6;
  int t6 = rest & 63;
  int rbase = (t6 >> 3) * 128, sbase = (t6 & 7) * 128;
  const float* W = which ? m2W : m1W;
  const float* bias = which ? m2b : m1b;
  u16* outg = which ? x2tg : x1tg;
  int t = threadIdx.x;
  // stage Bs + El once
  {
    int row = t >> 1, half = t & 1;
    const u32* gB = (const u32*)(xbg + (sbase + row) * 64 + half * 32);
    u32* dstB = (u32*)&Bs[row * 80 + half * 32];
#pragma unroll
    for (int k = 0; k < 16; ++k) dstB[k] = gB[k];
    int ab = which ? sbase : rbase;
    int bb = which ? rbase : sbase;
    const u32* gE = (const u32*)(eim + (size_t)(ab + row) * 1024 + bb + half * 64);
    u32* dstE = (u32*)&El[row * 132 + half * 64];
#pragma unroll
    for (int k = 0; k < 16; ++k) dstE[k] = gE[k];
  }
  int lane = t & 63, w = t >> 6;
  int q = lane >> 4, r = lane & 15;
  int wr = w >> 1, wc = w & 1;
  for (int ci = 0; ci < 4; ++ci) {
    int cl = cg * 4 + ci;
    int c = cbase + cl;
    if (t < 64) wsc[t] = W[t * 64 + c];
    __syncthreads();  // Bs/El ready (ci=0); prev As frag reads + Cs store reads done; wsc visible
    {
      int row = t >> 1, half = t & 1;
      const u32* ga = (const u32*)(xbg + (rbase + row) * 64 + half * 32);
      u32* dstA = (u32*)&As[row * 80 + half * 32];
#pragma unroll
      for (int k = 0; k < 16; ++k) {
        u32 u = ga[k];
        float f0 = bf2f((u16)(u & 0xffffu)) * wsc[half * 32 + 2 * k];
        float f1 = bf2f((u16)(u >> 16)) * wsc[half * 32 + 2 * k + 1];
        dstA[k] = (u32)f2bf(f0) | ((u32)f2bf(f1) << 16);
      }
    }
    __syncthreads();
    f32x4 z4 = {0.f, 0.f, 0.f, 0.f};
    f32x4 acc[4][4];
#pragma unroll
    for (int mi = 0; mi < 4; ++mi)
#pragma unroll
      for (int ni = 0; ni < 4; ++ni) acc[mi][ni] = z4;
#pragma unroll
    for (int ks = 0; ks < 2; ++ks) {
      bf16x8 af[4], bfr[4];
#pragma unroll
      for (int mi = 0; mi < 4; ++mi)
        af[mi] = *(const bf16x8*)&As[(wr * 64 + mi * 16 + r) * 80 + ks * 32 + q * 8];
#pragma unroll
      for (int ni = 0; ni < 4; ++ni)
        bfr[ni] = *(const bf16x8*)&Bs[(wc * 64 + ni * 16 + r) * 80 + ks * 32 + q * 8];
#pragma unroll
      for (int mi = 0; mi < 4; ++mi)
#pragma unroll
        for (int ni = 0; ni < 4; ++ni) acc[mi][ni] = MFMA16(af[mi], bfr[ni], acc[mi][ni]);
    }
    float w64 = W[64 * 64 + c];
    float bsv = bias[c];
#pragma unroll
    for (int mi = 0; mi < 4; ++mi) {
#pragma unroll
      for (int ni = 0; ni < 4; ++ni) {
        int col = wc * 64 + ni * 16 + r;
#pragma unroll
        for (int tt = 0; tt < 4; ++tt) {
          int row2 = wr * 64 + mi * 16 + q * 4 + tt;
          float e = (float)(which ? El[col * 132 + row2] : El[row2 * 132 + col]);
          acc[mi][ni][tt] = fmaxf(acc[mi][ni][tt] + e * w64 + bsv, 0.f);
        }
      }
    }
    u16* outp = outg + (size_t)cl * 1048576;
    // two 64-row passes through Cs -> full-line coalesced stores
#pragma unroll
    for (int p = 0; p < 2; ++p) {
      __syncthreads();  // prior Cs store reads done
      if (wr == p) {
#pragma unroll
        for (int mi = 0; mi < 4; ++mi)
#pragma unroll
          for (int ni = 0; ni < 4; ++ni) {
            int col = wc * 64 + ni * 16 + r;
#pragma unroll
            for (int tt = 0; tt < 4; ++tt) {
              int lrow = mi * 16 + q * 4 + tt;
              Cs[lrow * 140 + col] = f2bf(acc[mi][ni][tt]);
            }
          }
      }
      __syncthreads();
      {
        int rl = t >> 4, ch = t & 15;
#pragma unroll
        for (int it = 0; it < 4; ++it) {
          int row = it * 16 + rl;
          uint4 v = *(const uint4*)&Cs[row * 140 + ch * 8];
          *(uint4*)(outp + (size_t)(rbase + p * 64 + row) * 1024 + sbase + ch * 8) = v;
        }
      }
    }
  }
}

// ---------------- batched prod GEMM (16 channels per launch) ----------------
__global__ __launch_bounds__(256, 4) void k_prodgemm(
    const u16* __restrict__ x1tg, const u16* __restrict__ x2tg,
    u16* __restrict__ prod, int cbase) {
  __shared__ u16 pool[17408];
  int b = blockIdx.x;  // grid 1024 = 64 tiles x 16 ch (cl low bits)
  int cl = b & 15;
  int tile = b >> 4;
  int i0 = (tile >> 3) * 128, j0 = (tile & 7) * 128;
  const u16* Ap = x1tg + (size_t)cl * 1048576;
  const u16* Bp = x2tg + (size_t)cl * 1048576;
  u16* Pp = prod + (size_t)(cbase + cl) * 1048576;
  int t = threadIdx.x, lane = t & 63, w = t >> 6;
  int q = lane >> 4, r = lane & 15;
  int wr = w >> 1, wc = w & 1;
  int lrow = lane >> 3, lcol = (lane & 7) * 8;
  f32x4 z4 = {0.f, 0.f, 0.f, 0.f};
  f32x4 acc[4][4];
#pragma unroll
  for (int mi = 0; mi < 4; ++mi)
#pragma unroll
    for (int ni = 0; ni < 4; ++ni) acc[mi][ni] = z4;
  for (int kk = 0; kk < 1024; kk += 64) {
    __syncthreads();
#pragma unroll
    for (int s8 = 0; s8 < 4; ++s8) {
      int rowbase = w * 32 + s8 * 8;
      int grow = rowbase + lrow;
      __builtin_amdgcn_global_load_lds(
          (gas1)(Ap + (size_t)(i0 + grow) * 1024 + kk + lcol),
          (las3)&pool[rowbase * 64], 16, 0, 0);
      __builtin_amdgcn_global_load_lds(
          (gas1)(Bp + (size_t)(j0 + grow) * 1024 + kk + lcol),
          (las3)&pool[8192 + rowbase * 64], 16, 0, 0);
    }
    __syncthreads();
#pragma unroll
    for (int ks = 0; ks < 2; ++ks) {
      bf16x8 af[4], bfr[4];
#pragma unroll
      for (int mi = 0; mi < 4; ++mi)
        af[mi] = *(const bf16x8*)&pool[(wr * 64 + mi * 16 + r) * 64 + ks * 32 + q * 8];
#pragma unroll
      for (int ni = 0; ni < 4; ++ni)
        bfr[ni] = *(const bf16x8*)&pool[8192 + (wc * 64 + ni * 16 + r) * 64 + ks * 32 + q * 8];
#pragma unroll
      for (int mi = 0; mi < 4; ++mi)
#pragma unroll
        for (int ni = 0; ni < 4; ++ni) acc[mi][ni] = MFMA16(af[mi], bfr[ni], acc[mi][ni]);
    }
  }
  __syncthreads();
#pragma unroll
  for (int mi = 0; mi < 4; ++mi)
#pragma unroll
    for (int ni = 0; ni < 4; ++ni) {
      int col = wc * 64 + ni * 16 + r;
#pragma unroll
      for (int tt = 0; tt < 4; ++tt) {
        int row2 = wr * 64 + mi * 16 + q * 4 + tt;
        pool[row2 * 136 + col] = f2bf(acc[mi][ni][tt]);
      }
    }
  __syncthreads();
  {
    int rseg = t >> 4, cseg = t & 15;
#pragma unroll
    for (int it = 0; it < 8; ++it) {
      int row = it * 16 + rseg;
      uint4 v = *(const uint4*)&pool[row * 136 + cseg * 8];
      *(uint4*)(Pp + (size_t)(i0 + row) * 1024 + j0 + cseg * 8) = v;
    }
  }
}

// ---------------- T = [x_i*x_j | eim | prod] @ m3W + b3 (IN PLACE over prod) --
__global__ __launch_bounds__(256, 3) void k_buildT(
    const u16* __restrict__ xbg, const unsigned char* __restrict__ eim,
    u16* PT, const float* __restrict__ m3W, const float* __restrict__ m3b,
    float* __restrict__ S, float* __restrict__ SS) {
  __shared__ u16 A[64 * 136];
  __shared__ u16 Wt[64 * 136];
  __shared__ u16 scratch[64 * 66];
  __shared__ float xi[64];
  int i = blockIdx.x;  // grid 1024
  int t = threadIdx.x, lane = t & 63, w = t >> 6;
  int q = lane >> 4, r = lane & 15;
  {
    int zidx = i * 256 + t;
    if (zidx < 65536) { S[zidx] = 0.f; SS[zidx] = 0.f; }
  }
  if (t < 64) xi[t] = bf2f(xbg[i * 64 + t]);
  {
    int row = t >> 1, half = t & 1;
    int rsrc = row < 64 ? row : row + 1;  // skip eim row 64
    const float4* gw = (const float4*)(m3W + rsrc * 64 + half * 32);
#pragma unroll
    for (int k = 0; k < 8; ++k) {
      float4 f = gw[k];
      Wt[(half * 32 + 4 * k + 0) * 136 + row] = f2bf(f.x);
      Wt[(half * 32 + 4 * k + 1) * 136 + row] = f2bf(f.y);
      Wt[(half * 32 + 4 * k + 2) * 136 + row] = f2bf(f.z);
      Wt[(half * 32 + 4 * k + 3) * 136 + row] = f2bf(f.w);
    }
  }
  float w64c[4], b3c[4];
#pragma unroll
  for (int ni = 0; ni < 4; ++ni) {
    int cc = ni * 16 + r;
    w64c[ni] = m3W[64 * 64 + cc];
    b3c[ni] = m3b[cc];
  }
  for (int jc = 0; jc < 16; ++jc) {
    int j0 = jc * 64;
    __syncthreads();
    {
      int jj = t >> 2, quar = t & 3;
      const u32* gx = (const u32*)(xbg + (j0 + jj) * 64 + quar * 16);
      u32* dst = (u32*)&A[jj * 136 + quar * 16];
#pragma unroll
      for (int k = 0; k < 8; ++k) {
        u32 u = gx[k];
        float f0 = bf2f((u16)(u & 0xffffu)) * xi[quar * 16 + 2 * k];
        float f1 = bf2f((u16)(u >> 16)) * xi[quar * 16 + 2 * k + 1];
        dst[k] = (u32)f2bf(f0) | ((u32)f2bf(f1) << 16);
      }
      int p = t >> 2, pt = t & 3;
      const uint4* gp = (const uint4*)(PT + (size_t)p * 1048576 + (size_t)i * 1024 + j0 + pt * 16);
      uint4 v0 = gp[0];
      uint2 v1 = ((const uint2*)gp)[2];
      uint2 v2 = ((const uint2*)gp)[3];
      u32* sw = (u32*)&scratch[p * 66 + pt * 16];
      sw[0] = v0.x; sw[1] = v0.y; sw[2] = v0.z; sw[3] = v0.w;
      sw[4] = v1.x; sw[5] = v1.y; sw[6] = v2.x; sw[7] = v2.y;
    }
    __syncthreads();
    {
#pragma unroll
      for (int jj2 = 0; jj2 < 8; ++jj2) {
        int jr = w * 16 + jj2 * 2;
        u32 two = *(const u32*)&scratch[lane * 66 + jr];
        A[jr * 136 + 64 + lane] = (u16)(two & 0xffffu);
        A[(jr + 1) * 136 + 64 + lane] = (u16)(two >> 16);
      }
    }
    __syncthreads();
    f32x4 z4 = {0.f, 0.f, 0.f, 0.f};
    f32x4 acc[4];
#pragma unroll
    for (int ni = 0; ni < 4; ++ni) acc[ni] = z4;
#pragma unroll
    for (int ks = 0; ks < 4; ++ks) {
      bf16x8 af, bfr[4];
      af = *(const bf16x8*)&A[(w * 16 + r) * 136 + ks * 32 + q * 8];
#pragma unroll
      for (int ni = 0; ni < 4; ++ni)
        bfr[ni] = *(const bf16x8*)&Wt[(ni * 16 + r) * 136 + ks * 32 + q * 8];
#pragma unroll
      for (int ni = 0; ni < 4; ++ni) acc[ni] = MFMA16(af, bfr[ni], acc[ni]);
    }
#pragma unroll
    for (int tt = 0; tt < 4; ++tt) {
      int jj = w * 16 + q * 4 + tt;
      float ev = (float)eim[(size_t)i * 1024 + j0 + jj];
#pragma unroll
      for (int ni = 0; ni < 4; ++ni)
        acc[ni][tt] = acc[ni][tt] + ev * w64c[ni] + b3c[ni];
    }
    __syncthreads();
#pragma unroll
    for (int ni = 0; ni < 4; ++ni) {
      int cc = ni * 16 + r;
#pragma unroll
      for (int tt = 0; tt < 4; ++tt) {
        int jj = w * 16 + q * 4 + tt;
        A[cc * 136 + jj] = f2bf(acc[ni][tt]);
      }
    }
    __syncthreads();
    {
      int pl = t >> 3, off = (t & 7) * 8;
#pragma unroll
      for (int k = 0; k < 2; ++k) {
        int plane = k * 32 + pl;
        uint4 v = *(const uint4*)&A[plane * 136 + off];
        *(uint4*)(PT + (size_t)plane * 1048576 + (size_t)i * 1024 + j0 + off) = v;
      }
    }
  }
}

// ---------------- graph-norm stats, pass 1: coalesced partial sums ----------
__global__ void k_stats(const u16* __restrict__ Tg, float* __restrict__ S,
                        float* __restrict__ SS) {
  int b = blockIdx.x;  // grid 512 = 64 c x 8 i-chunks
  int c = b >> 3, ic = b & 7;
  int t = threadIdx.x;
  const u16* base = Tg + (size_t)c * 1048576 + (size_t)ic * 131072 + t * 4;
  float s0 = 0.f, s1 = 0.f, s2 = 0.f, s3 = 0.f;
  float q0 = 0.f, q1 = 0.f, q2 = 0.f, q3 = 0.f;
  for (int ii = 0; ii < 128; ++ii) {
    uint2 u = *(const uint2*)(base + (size_t)ii * 1024);
    float v0 = bf2f((u16)(u.x & 0xffffu)), v1 = bf2f((u16)(u.x >> 16));
    float v2 = bf2f((u16)(u.y & 0xffffu)), v3 = bf2f((u16)(u.y >> 16));
    s0 += v0; q0 += v0 * v0;
    s1 += v1; q1 += v1 * v1;
    s2 += v2; q2 += v2 * v2;
    s3 += v3; q3 += v3 * v3;
  }
  int base2 = c * 1024 + t * 4;
  atomicAdd(&S[base2 + 0], s0);
  atomicAdd(&S[base2 + 1], s1);
  atomicAdd(&S[base2 + 2], s2);
  atomicAdd(&S[base2 + 3], s3);
  atomicAdd(&SS[base2 + 0], q0);
  atomicAdd(&SS[base2 + 1], q1);
  atomicAdd(&SS[base2 + 2], q2);
  atomicAdd(&SS[base2 + 3], q3);
}

// ---------------- graph-norm stats, pass 2: finalize ----------
__global__ void k_statsfin(const float* __restrict__ S, const float* __restrict__ SS,
                           const float* __restrict__ gn3w, const float* __restrict__ gn3b,
                           const float* __restrict__ gn3a,
                           float* __restrict__ normA, float* __restrict__ normB) {
  int idx = blockIdx.x * 256 + threadIdx.x;  // grid 256 -> 65536 = j*64+c
  int c = idx & 63, j = idx >> 6;
  float sum = S[c * 1024 + j];
  float ssum = SS[c * 1024 + j];
  float m = sum * (1.f / 1024.f);
  float a = gn3a[c];
  float var = ssum * (1.f / 1024.f) - (2.f * a - a * a) * m * m;
  float sc = gn3w[c] * rsqrtf(fmaxf(var, 0.f) + 1e-5f);
  normA[idx] = sc;
  normB[idx] = gn3b[c] - sc * a * m;
}

// ---------------- gather + symmetric product + final dot ----------------
__global__ void k_final(const u16* __restrict__ Tg, const float* __restrict__ normA,
                        const float* __restrict__ normB, const int* __restrict__ pos,
                        const float* __restrict__ ldW, const float* __restrict__ ldb,
                        float* __restrict__ out) {
  int t = threadIdx.x, w = t >> 6, lane = t & 63;  // grid 2048 x 256, wave/pos
  int p = blockIdx.x * 4 + w;
  int i = pos[2 * p], j = pos[2 * p + 1];
  float t1 = bf2f(Tg[(size_t)lane * 1048576 + (size_t)i * 1024 + j]);
  float y1 = fmaxf(normA[j * 64 + lane] * t1 + normB[j * 64 + lane], 0.f);
  float t2 = bf2f(Tg[(size_t)lane * 1048576 + (size_t)j * 1024 + i]);
  float y2 = fmaxf(normA[i * 64 + lane] * t2 + normB[i * 64 + lane], 0.f);
  float z = y1 * y2 * ldW[lane];
#pragma unroll
  for (int off = 32; off > 0; off >>= 1) z += __shfl_down(z, off, 64);
  if (lane == 0) out[p] = z + ldb[0];
}

extern "C" void kernel_launch(void* const* d_in, const int* in_sizes, int n_in,
                              void* d_out, int out_size, void* d_ws, size_t ws_size,
                              hipStream_t stream) {
  const int* xids   = (const int*)d_in[0];
  const int* ei     = (const int*)d_in[1];
  const int* pos    = (const int*)d_in[2];
  const float* emb  = (const float*)d_in[3];
  const float* gW0  = (const float*)d_in[4];
  const float* gb0  = (const float*)d_in[5];
  const float* gnw0 = (const float*)d_in[6];
  const float* gnb0 = (const float*)d_in[7];
  const float* gna0 = (const float*)d_in[8];
  const float* gW1  = (const float*)d_in[9];
  const float* gb1  = (const float*)d_in[10];
  const float* gnw1 = (const float*)d_in[11];
  const float* gnb1 = (const float*)d_in[12];
  const float* gna1 = (const float*)d_in[13];
  const float* m1W  = (const float*)d_in[14];
  const float* m1b  = (const float*)d_in[15];
  const float* m2W  = (const float*)d_in[16];
  const float* m2b  = (const float*)d_in[17];
  const float* m3W  = (const float*)d_in[18];
  const float* m3b  = (const float*)d_in[19];
  const float* gn3w = (const float*)d_in[20];
  const float* gn3b = (const float*)d_in[21];
  const float* gn3a = (const float*)d_in[22];
  const float* ldW  = (const float*)d_in[23];
  const float* ldb  = (const float*)d_in[24];

  char* ws = (char*)d_ws;
  float* xf   = (float*)(ws + 0);
  float* h    = (float*)(ws + 262144);
  float* agg  = (float*)(ws + 524288);
  float* deg  = (float*)(ws + 786432);
  u16*   xb   = (u16*)(ws + 790528);
  unsigned char* eim = (unsigned char*)(ws + 921600);
  float* normA = (float*)(ws + 1970176);
  float* normB = (float*)(ws + 2232320);
  u16* x1tg = (u16*)(ws + 2494464);
  u16* x2tg = (u16*)(ws + 36048896);
  u16* prod = (u16*)(ws + 69603328);  // later overwritten in place by T
  float* Sp  = (float*)x1tg;          // stats partials overlay dead x1tg
  float* SSp = Sp + 65536;
  float* out = (float*)d_out;

  k_setup<<<1024, 256, 0, stream>>>(xids, emb, xf, deg, (u32*)eim);
  k_edges<<<64, 256, 0, stream>>>(ei, deg, eim);
  // GCN layer 0
  k_gemm_node<<<1024, 64, 0, stream>>>(xf, gW0, gb0, deg, h, agg);
  k_agg<<<4096, 256, 0, stream>>>(ei, deg, h, agg);
  k_gnorm<<<64, 256, 0, stream>>>(agg, gnw0, gnb0, gna0, xf, xb, 0);
  // GCN layer 1
  k_gemm_node<<<1024, 64, 0, stream>>>(xf, gW1, gb1, deg, h, agg);
  k_agg<<<4096, 256, 0, stream>>>(ei, deg, h, agg);
  k_gnorm<<<64, 256, 0, stream>>>(agg, gnw1, gnb1, gna1, xf, xb, 1);
  // pairwise maps + batched 1024^3 GEMM, 4 channel-groups of 16
  for (int g = 0; g < 4; ++g) {
    k_build12<<<512, 256, 0, stream>>>(xb, eim, m1W, m1b, m2W, m2b, x1tg, x2tg, g * 16);
    k_prodgemm<<<1024, 256, 0, stream>>>(x1tg, x2tg, prod, g * 16);
  }
  // T tensor (in place over prod) + stats + final
  k_buildT<<<1024, 256, 0, stream>>>(xb, eim, prod, m3W, m3b, Sp, SSp);
  k_stats<<<512, 256, 0, stream>>>(prod, Sp, SSp);
  k_statsfin<<<256, 256, 0, stream>>>(Sp, SSp, gn3w, gn3b, gn3a, normA, normB);
  k_final<<<2048, 256, 0, stream>>>(prod, normA, normB, pos, ldW, ldb, out);
}